// Round 6
// baseline (1043.204 us; speedup 1.0000x reference)
//
#include <hip/hip_runtime.h>
#include <stdint.h>

// Problem dims (from reference)
#define D_MODEL 1024
#define D_FF    4096
#define NTOK    16384   // BATCH*SEQ = 4*4096
#define SEQ     4096

typedef __bf16 bf16x8 __attribute__((ext_vector_type(8)));
typedef float  f32x4  __attribute__((ext_vector_type(4)));

typedef __attribute__((address_space(1))) void gvoid;
typedef __attribute__((address_space(3))) void svoid;

__device__ __forceinline__ unsigned short f2bf(float f) {
  union { float f; uint32_t u; } v; v.f = f;
  uint32_t u = v.u;
  u += 0x7FFFu + ((u >> 16) & 1u);   // round-to-nearest-even
  return (unsigned short)(u >> 16);
}
__device__ __forceinline__ float bf2f(unsigned short h) {
  union { uint32_t u; float f; } v; v.u = ((uint32_t)h) << 16;
  return v.f;
}

// async global->LDS, 16B per lane (dest is wave-uniform base + lane*16)
__device__ __forceinline__ void gload16(const void* g, void* l) {
  __builtin_amdgcn_global_load_lds((gvoid*)g, (svoid*)l, 16, 0, 0);
}

__device__ __forceinline__ float fast_sigmoid(float x) {
  return __builtin_amdgcn_rcpf(1.f + __expf(-x));
}

// ---------------- fp32 -> bf16 weight conversion ----------------
__global__ __launch_bounds__(256) void cvt_k(const float* __restrict__ S,
                                             unsigned short* __restrict__ D, int n4) {
  int i = blockIdx.x * 256 + threadIdx.x;
  if (i < n4) {
    float4 f = reinterpret_cast<const float4*>(S)[i];
    ushort4 o;
    o.x = f2bf(f.x); o.y = f2bf(f.y); o.z = f2bf(f.z); o.w = f2bf(f.w);
    reinterpret_cast<ushort4*>(D)[i] = o;
  }
}

// interleave wg/wu rows: D row 2i = G[i], row 2i+1 = U[i]  (rows of length 1024)
__global__ __launch_bounds__(256) void cvt_il_k(const float* __restrict__ G,
                                                const float* __restrict__ U,
                                                unsigned short* __restrict__ D) {
  int i = blockIdx.x * 256 + threadIdx.x;      // ushort4 index; 8192*1024/4 total
  const int row = i >> 8;                      // 256 ushort4 per 1024-row
  const int c4  = i & 255;
  const float* src = ((row & 1) ? U : G) + (size_t)(row >> 1) * 1024 + c4 * 4;
  float4 f = *reinterpret_cast<const float4*>(src);
  ushort4 o;
  o.x = f2bf(f.x); o.y = f2bf(f.y); o.z = f2bf(f.z); o.w = f2bf(f.w);
  reinterpret_cast<ushort4*>(D)[i] = o;
}

// ---------------- RMSNorm (+ optional scale-gate softmax) ----------------
template<bool SG>
__global__ __launch_bounds__(256) void rmsnorm_k(
    const float* __restrict__ X, const float* __restrict__ W,
    const float* __restrict__ SGW,
    unsigned short* __restrict__ H, float* __restrict__ SCL)
{
  const int n = blockIdx.x;
  const int t = threadIdx.x;
  float4 x = reinterpret_cast<const float4*>(X + (size_t)n * D_MODEL)[t];
  float4 w = reinterpret_cast<const float4*>(W)[t];
  float4 hw;
  hw.x = x.x * w.x; hw.y = x.y * w.y; hw.z = x.z * w.z; hw.w = x.w * w.w;
  float ss = x.x*x.x + x.y*x.y + x.z*x.z + x.w*x.w;
  float p0 = 0.f, p1 = 0.f, p2 = 0.f;
  if (SG) {
    float4 s0 = reinterpret_cast<const float4*>(SGW)[t];
    float4 s1 = reinterpret_cast<const float4*>(SGW + D_MODEL)[t];
    float4 s2 = reinterpret_cast<const float4*>(SGW + 2 * D_MODEL)[t];
    p0 = hw.x*s0.x + hw.y*s0.y + hw.z*s0.z + hw.w*s0.w;
    p1 = hw.x*s1.x + hw.y*s1.y + hw.z*s1.z + hw.w*s1.w;
    p2 = hw.x*s2.x + hw.y*s2.y + hw.z*s2.z + hw.w*s2.w;
  }
  #pragma unroll
  for (int off = 32; off > 0; off >>= 1) {
    ss += __shfl_xor(ss, off);
    if (SG) {
      p0 += __shfl_xor(p0, off);
      p1 += __shfl_xor(p1, off);
      p2 += __shfl_xor(p2, off);
    }
  }
  __shared__ float red[4][4];
  const int wid = t >> 6;
  if ((t & 63) == 0) { red[wid][0] = ss; red[wid][1] = p0; red[wid][2] = p1; red[wid][3] = p2; }
  __syncthreads();
  ss = red[0][0] + red[1][0] + red[2][0] + red[3][0];
  const float r = rsqrtf(ss * (1.0f / D_MODEL) + 1e-6f);
  ushort4 h4;
  h4.x = f2bf(hw.x * r); h4.y = f2bf(hw.y * r); h4.z = f2bf(hw.z * r); h4.w = f2bf(hw.w * r);
  reinterpret_cast<ushort4*>(H + (size_t)n * D_MODEL)[t] = h4;
  if (SG && t == 0) {
    float l0 = (red[0][1] + red[1][1] + red[2][1] + red[3][1]) * r;
    float l1 = (red[0][2] + red[1][2] + red[2][2] + red[3][2]) * r;
    float l2 = (red[0][3] + red[1][3] + red[2][3] + red[3][3]) * r;
    float mx = fmaxf(l0, fmaxf(l1, l2));
    float e0 = expf(l0 - mx), e1 = expf(l1 - mx), e2 = expf(l2 - mx);
    float inv = 1.f / (e0 + e1 + e2);
    SCL[n * 3 + 0] = e0 * inv; SCL[n * 3 + 1] = e1 * inv; SCL[n * 3 + 2] = e2 * inv;
  }
}

// ---------------- multi-scale causal depthwise conv + gate mix ----------------
__global__ __launch_bounds__(256) void conv_k(
    const unsigned short* __restrict__ GV,   // [NTOK, 2048] bf16: gate | val
    const float* __restrict__ SCL,           // [NTOK, 3]
    const float* __restrict__ W3, const float* __restrict__ W5, const float* __restrict__ W7,
    unsigned short* __restrict__ Y)          // [NTOK, 1024] bf16
{
  const int n = blockIdx.x;
  const int t = threadIdx.x;
  const int d0 = t * 4;
  const int s = n & (SEQ - 1);
  const unsigned short* vbase = GV + (size_t)n * (2 * D_MODEL) + D_MODEL + d0;
  float v[7][4];
  #pragma unroll
  for (int j = 0; j < 7; ++j) {
    const int tap = 6 - j;
    if (tap <= s) {
      ushort4 u = *reinterpret_cast<const ushort4*>(vbase - (size_t)tap * (2 * D_MODEL));
      v[j][0] = bf2f(u.x); v[j][1] = bf2f(u.y); v[j][2] = bf2f(u.z); v[j][3] = bf2f(u.w);
    } else {
      v[j][0] = 0.f; v[j][1] = 0.f; v[j][2] = 0.f; v[j][3] = 0.f;
    }
  }
  ushort4 gb = *reinterpret_cast<const ushort4*>(GV + (size_t)n * (2 * D_MODEL) + d0);
  float gf[4] = { bf2f(gb.x), bf2f(gb.y), bf2f(gb.z), bf2f(gb.w) };
  const float sc0 = SCL[n * 3 + 0], sc1 = SCL[n * 3 + 1], sc2 = SCL[n * 3 + 2];
  ushort4 out;
  unsigned short o[4];
  #pragma unroll
  for (int i = 0; i < 4; ++i) {
    const int d = d0 + i;
    float c3 = W3[d*3+0]*v[4][i] + W3[d*3+1]*v[5][i] + W3[d*3+2]*v[6][i];
    float c5 = W5[d*5+0]*v[2][i] + W5[d*5+1]*v[3][i] + W5[d*5+2]*v[4][i]
             + W5[d*5+3]*v[5][i] + W5[d*5+4]*v[6][i];
    float c7 = 0.f;
    #pragma unroll
    for (int j = 0; j < 7; ++j) c7 += W7[d*7+j] * v[j][i];
    const float g = fast_sigmoid(gf[i]);
    o[i] = f2bf((sc0 * c3 + sc1 * c5 + sc2 * c7) * g);
  }
  out.x = o[0]; out.y = o[1]; out.z = o[2]; out.w = o[3];
  reinterpret_cast<ushort4*>(Y + (size_t)n * D_MODEL)[t] = out;
}

// ---------------- 256x256 8-phase BT GEMM: C[M,N] = A[M,K] * B[N,K]^T ----------------
// r6: LDS reads restructured for MFMA overlap. All 24 ds_read_b128 of a slot
// are issued in ONE burst at the slot's first phase (order: A_H0(8), B_H0(4),
// B_H1(4), A_H1(8) -> regs a0,b0,b1,a1). MFMA clusters gate on counted
// lgkmcnt (DS completes in-order): (0,0)@lgkm(12), (0,1)@lgkm(8),
// (1,1)/(1,0)@lgkm(0). 12 of 24 reads drain UNDER the first two MFMA
// clusters instead of serializing the whole CU. Staging schedule + vmcnt(6)
// accounting identical to r5 (verified race-free); final iter peeled with
// vmcnt(0) at the slot boundary.
// LDS layout: slot s (s<<16) | A half h (h<<14) | B at 32768 + (h<<14);
// row r: r*128 B; 16B chunk c holds global chunk c^(r&7) (pre-swizzled src).

#define EPI_BF16      0
#define EPI_RES       1
#define EPI_SWIGLU_IL 2

#define STAGE_A(tt, h) do { if ((tt) < nt) { \
    char* d_ = dstBase + (((tt)&1) << 16) + ((h) << 14); \
    const unsigned short* s_ = aSrc + (size_t)((h)*128) * K + (tt)*64; \
    gload16(s_, d_); gload16(s_ + (size_t)64 * K, d_ + 8192); } } while(0)

#define STAGE_B(tt, h) do { if ((tt) < nt) { \
    char* d_ = dstBase + (((tt)&1) << 16) + 32768 + ((h) << 14); \
    const unsigned short* s_ = bSrc + (size_t)((h)*32) * K + (tt)*64; \
    gload16(s_, d_); gload16(s_ + (size_t)128 * K, d_ + 8192); } } while(0)

// raw ds_read_b128: base VGPR + literal offset
#define DSR(dst, base, IMM) \
  asm volatile("ds_read_b128 %0, %1 offset:" #IMM : "=v"(dst) : "v"(base))

#define LOAD_A_H0(S) do { \
  DSR(a0[0][0], aA##S##k0, 0);    DSR(a0[0][1], aA##S##k1, 0); \
  DSR(a0[1][0], aA##S##k0, 2048); DSR(a0[1][1], aA##S##k1, 2048); \
  DSR(a0[2][0], aA##S##k0, 4096); DSR(a0[2][1], aA##S##k1, 4096); \
  DSR(a0[3][0], aA##S##k0, 6144); DSR(a0[3][1], aA##S##k1, 6144); } while(0)

#define LOAD_A_H1(S) do { \
  DSR(a1[0][0], aA##S##k0, 8192);  DSR(a1[0][1], aA##S##k1, 8192); \
  DSR(a1[1][0], aA##S##k0, 10240); DSR(a1[1][1], aA##S##k1, 10240); \
  DSR(a1[2][0], aA##S##k0, 12288); DSR(a1[2][1], aA##S##k1, 12288); \
  DSR(a1[3][0], aA##S##k0, 14336); DSR(a1[3][1], aA##S##k1, 14336); } while(0)

#define LOAD_B_H0(S) do { \
  DSR(b0[0][0], bB##S##k0, 0);    DSR(b0[0][1], bB##S##k1, 0); \
  DSR(b0[1][0], bB##S##k0, 2048); DSR(b0[1][1], bB##S##k1, 2048); } while(0)

#define LOAD_B_H1(S) do { \
  DSR(b1[0][0], bB##S##k0, 16384); DSR(b1[0][1], bB##S##k1, 16384); \
  DSR(b1[1][0], bB##S##k0, 18432); DSR(b1[1][1], bB##S##k1, 18432); } while(0)

#define LOAD_SLOT(S) do { LOAD_A_H0(S); LOAD_B_H0(S); LOAD_B_H1(S); LOAD_A_H1(S); } while(0)

#define MMAQ(AR, BR, MQ, NQ) do { \
  _Pragma("unroll") for (int f_ = 0; f_ < 4; ++f_) \
  _Pragma("unroll") for (int e_ = 0; e_ < 2; ++e_) { \
    acc[(MQ)*4+f_][(NQ)*2+e_] = __builtin_amdgcn_mfma_f32_16x16x32_bf16( \
        AR[f_][0], BR[e_][0], acc[(MQ)*4+f_][(NQ)*2+e_], 0, 0, 0); \
    acc[(MQ)*4+f_][(NQ)*2+e_] = __builtin_amdgcn_mfma_f32_16x16x32_bf16( \
        AR[f_][1], BR[e_][1], acc[(MQ)*4+f_][(NQ)*2+e_], 0, 0, 0); \
  } } while(0)

// counted-lgkm phase gate: N = ds_reads allowed to remain outstanding
#define PH_MID(N) \
  __builtin_amdgcn_s_barrier(); \
  asm volatile("s_waitcnt lgkmcnt(" #N ")" ::: "memory"); \
  __builtin_amdgcn_sched_barrier(0); \
  __builtin_amdgcn_s_setprio(1)

#define PHASE_END() \
  __builtin_amdgcn_s_setprio(0); \
  __builtin_amdgcn_s_barrier()

#define PHASE_END_VM() \
  __builtin_amdgcn_s_setprio(0); \
  asm volatile("s_waitcnt vmcnt(6)" ::: "memory"); \
  __builtin_amdgcn_s_barrier()

#define PHASE_END_VM0() \
  __builtin_amdgcn_s_setprio(0); \
  asm volatile("s_waitcnt vmcnt(0)" ::: "memory"); \
  __builtin_amdgcn_s_barrier()

template<int EPI>
__global__ __launch_bounds__(512, 2) void gemm256_k(
    const unsigned short* __restrict__ A,
    const unsigned short* __restrict__ B0g,
    const float* __restrict__ RES,
    void* __restrict__ OUT,
    int M, int N, int K)
{
  __shared__ uint4 lds4[8192];   // 128 KB, LDS offset 0
  char* lbase = (char*)lds4;

  const int tid  = threadIdx.x;
  const int lane = tid & 63;
  const int wid  = tid >> 6;
  const int wm   = wid >> 2;        // 0..1
  const int wn   = wid & 3;         // 0..3
  const int l15 = lane & 15, l4 = lane >> 4, l7 = lane & 7;
  const int m0 = blockIdx.x * 256;
  const int n0 = blockIdx.y * 256;
  const int nt = K >> 6;            // always even, >= 16 here

  // staging: thread covers local row r0=tid>>3 (+64 for 2nd load), chunk slot
  // tid&7 which must hold global chunk (tid&7)^(r0&7)  (pre-swizzled source).
  const int r0 = tid >> 3;
  const int kc = (tid & 7) ^ (r0 & 7);
  const unsigned short* aSrc = A + (size_t)(m0 + r0) * K + kc * 8;
  const unsigned short* bSrc = B0g + (size_t)(n0 + (r0 >> 5) * 64 + (r0 & 31)) * K + kc * 8;
  char* dstBase = lbase + tid * 16;

  // fragment-read base addresses (raw LDS byte offsets; object at offset 0)
  const unsigned colswz = (unsigned)((l4 ^ l7) << 4);
  const unsigned aA0k0 = (unsigned)((wm << 14) + l15 * 128) + colswz;
  const unsigned aA0k1 = aA0k0 ^ 0x40u;        // kk=1: chunk (4+l4)^l7 = (l4^l7)^4
  const unsigned aA1k0 = aA0k0 + 65536u;
  const unsigned aA1k1 = aA0k1 + 65536u;
  const unsigned bB0k0 = (unsigned)(32768 + (wn * 32 + l15) * 128) + colswz;
  const unsigned bB0k1 = bB0k0 ^ 0x40u;
  const unsigned bB1k0 = bB0k0 + 65536u;
  const unsigned bB1k1 = bB0k1 + 65536u;

  f32x4 acc[8][4];
  #pragma unroll
  for (int i = 0; i < 8; ++i)
    #pragma unroll
    for (int j = 0; j < 4; ++j)
      #pragma unroll
      for (int r = 0; r < 4; ++r) acc[i][j][r] = 0.f;

  bf16x8 a0[4][2], a1[4][2], b0[2][2], b1[2][2];

  // prologue: t0 fully + t1.{A0,A1,B1}; t1.B0 comes at pi0 of iter 0
  STAGE_A(0, 0); STAGE_A(0, 1); STAGE_B(0, 0); STAGE_B(0, 1);
  STAGE_A(1, 0); STAGE_A(1, 1); STAGE_B(1, 1);
  asm volatile("s_waitcnt vmcnt(6)" ::: "memory");
  __builtin_amdgcn_s_barrier();

  // -------- main loop: all t with t+2 < nt (full prefetch depth) --------
  for (int t = 0; t + 2 < nt; t += 2) {
    // pi0: tile t (slot0) — issue ALL 24 slot reads, gate on first 12
    LOAD_SLOT(0);
    STAGE_B(t + 1, 0);
    PH_MID(12); MMAQ(a0, b0, 0, 0); PHASE_END();
    // pi1: (0,1) — b1 ready once <=8 outstanding (a1 drains under MFMA)
    STAGE_A(t + 2, 0);
    PH_MID(8); MMAQ(a0, b1, 0, 1); PHASE_END();
    // pi2: (1,1)
    STAGE_A(t + 2, 1);
    PH_MID(0); MMAQ(a1, b1, 1, 1); PHASE_END();
    // pi3: (1,0)
    STAGE_B(t + 2, 1);
    PH_MID(0); MMAQ(a1, b0, 1, 0); PHASE_END_VM();
    // pi4: tile t+1 (slot1)
    LOAD_SLOT(1);
    STAGE_B(t + 2, 0);
    PH_MID(12); MMAQ(a0, b0, 0, 0); PHASE_END();
    // pi5
    STAGE_A(t + 3, 0);
    PH_MID(8); MMAQ(a0, b1, 0, 1); PHASE_END();
    // pi6
    STAGE_A(t + 3, 1);
    PH_MID(0); MMAQ(a1, b1, 1, 1); PHASE_END();
    // pi7
    STAGE_B(t + 3, 1);
    PH_MID(0); MMAQ(a1, b0, 1, 0); PHASE_END_VM();
  }

  // -------- peeled final iteration (t = nt-2): no beyond-range stages;
  // queue is shallow so drain with vmcnt(0) at the slot boundary --------
  {
    // pi0: tile nt-2 (slot0) — fully landed via previous iter's pi7 vmcnt(6)
    LOAD_SLOT(0);
    STAGE_B(nt - 1, 0);
    PH_MID(12); MMAQ(a0, b0, 0, 0); PHASE_END();
    // pi1
    PH_MID(8); MMAQ(a0, b1, 0, 1); PHASE_END();
    // pi2
    PH_MID(0); MMAQ(a1, b1, 1, 1); PHASE_END();
    // pi3 — drain everything so tile nt-1 is fully resident before pi4
    PH_MID(0); MMAQ(a1, b0, 1, 0); PHASE_END_VM0();
    // pi4: tile nt-1 (slot1)
    LOAD_SLOT(1);
    PH_MID(12); MMAQ(a0, b0, 0, 0); PHASE_END();
    // pi5
    PH_MID(8); MMAQ(a0, b1, 0, 1); PHASE_END();
    // pi6
    PH_MID(0); MMAQ(a1, b1, 1, 1); PHASE_END();
    // pi7
    PH_MID(0); MMAQ(a1, b0, 1, 0); PHASE_END();
  }

  // keep LDS stores observable (never taken; M>0 always) — prevents DCE of
  // global_load_lds since no compiler-visible LDS reads remain.
  if (M < -1) ((float*)OUT)[tid] = ((float*)lds4)[tid];

  // epilogue: C/D fragment layout col=lane&15, row=(lane>>4)*4+rr
  const int cr = (lane >> 4) * 4;
  const int cc = lane & 15;
  #pragma unroll
  for (int F = 0; F < 8; ++F)
    #pragma unroll
    for (int E = 0; E < 4; ++E)
      #pragma unroll
      for (int rr = 0; rr < 4; ++rr) {
        const int grow = m0 + wm * 128 + (F >> 2) * 64 + (F & 3) * 16 + cr + rr;
        const int gcol = n0 + wn * 64 + (E >> 1) * 32 + (E & 1) * 16 + cc;
        const float v = acc[F][E][rr];
        if (EPI == EPI_BF16) {
          ((unsigned short*)OUT)[(size_t)grow * N + gcol] = f2bf(v);
        } else if (EPI == EPI_RES) {
          const size_t idx = (size_t)grow * N + gcol;
          ((float*)OUT)[idx] = RES[idx] + v;
        } else {  // EPI_SWIGLU_IL: even cc holds g, odd cc holds u for ff=gcol>>1
          const float pv = __shfl_xor(v, 1);
          const float g = (cc & 1) ? pv : v;
          const float u = (cc & 1) ? v : pv;
          const float o = g * fast_sigmoid(g) * u;
          unsigned int ob = f2bf(o);
          const unsigned int o2 = __shfl_xor((int)ob, 2);  // lane 4j gets ff+1's value
          if ((cc & 3) == 0) {
            const int ff = gcol >> 1;                      // even ff
            *reinterpret_cast<unsigned int*>(
                &((unsigned short*)OUT)[(size_t)grow * (D_FF) + ff]) = ob | (o2 << 16);
          }
        }
      }
}

// ---------------- launch ----------------
extern "C" void kernel_launch(void* const* d_in, const int* in_sizes, int n_in,
                              void* d_out, int out_size, void* d_ws, size_t ws_size,
                              hipStream_t stream)
{
  const float* x    = (const float*)d_in[0];
  const float* ln1w = (const float*)d_in[1];
  const float* ln2w = (const float*)d_in[2];
  const float* wf   = (const float*)d_in[3];
  const float* wm   = (const float*)d_in[4];
  const float* wco  = (const float*)d_in[5];
  const float* sgw  = (const float*)d_in[6];
  const float* upw  = (const float*)d_in[7];   // [2048,1024]
  const float* dnw  = (const float*)d_in[8];   // [1024,1024]
  const float* wg   = (const float*)d_in[9];   // [4096,1024]
  const float* wu   = (const float*)d_in[10];  // [4096,1024]
  const float* wo   = (const float*)d_in[11];  // [1024,4096]

  char* ws = (char*)d_ws;
  size_t off = 0;
  auto alloc = [&](size_t bytes) -> void* {
    void* p = ws + off;
    off += (bytes + 255) & ~(size_t)255;
    return p;
  };
  unsigned short* wb_up = (unsigned short*)alloc((size_t)2048 * 1024 * 2);
  unsigned short* wb_dn = (unsigned short*)alloc((size_t)1024 * 1024 * 2);
  unsigned short* wb_il = (unsigned short*)alloc((size_t)8192 * 1024 * 2);  // interleaved wg/wu
  unsigned short* wb_wo = (unsigned short*)alloc((size_t)1024 * 4096 * 2);
  float*          scl   = (float*)alloc((size_t)NTOK * 3 * 4);
  unsigned short* h2b   = (unsigned short*)alloc((size_t)NTOK * D_MODEL * 2);
  // 128MB region: h | gv | y live before the SwiGLU GEMM; gu aliases all three afterwards
  char* big = (char*)alloc((size_t)NTOK * 4096 * 2);
  unsigned short* hb  = (unsigned short*)big;                                  // [NTOK,1024]
  unsigned short* gvb = (unsigned short*)(big + (size_t)NTOK * 1024 * 2);      // [NTOK,2048]
  unsigned short* yb  = (unsigned short*)(big + (size_t)NTOK * 3072 * 2);      // [NTOK,1024]
  unsigned short* gub = (unsigned short*)big;                                  // [NTOK,4096]
  float* x1 = (float*)d_out;  // x after first residual lives in d_out

  // weights -> bf16
  cvt_k<<<2048, 256, 0, stream>>>(upw, wb_up, 2048 * 1024 / 4);
  cvt_k<<<1024, 256, 0, stream>>>(dnw, wb_dn, 1024 * 1024 / 4);
  cvt_il_k<<<8192, 256, 0, stream>>>(wg, wu, wb_il);
  cvt_k<<<4096, 256, 0, stream>>>(wo, wb_wo, 1024 * 4096 / 4);

  // 1) h = rmsnorm(x, ln1); scale_w = softmax(h @ sg_w^T)
  rmsnorm_k<true><<<NTOK, 256, 0, stream>>>(x, ln1w, sgw, hb, scl);
  // 2) gv = h @ up_w^T  [NTOK, 2048] bf16
  gemm256_k<EPI_BF16><<<dim3(64, 8), 512, 0, stream>>>(hb, wb_up, nullptr, gvb, NTOK, 2048, 1024);
  // 3) y = (sum_k scale_k * conv_k(val)) * sigmoid(gate)
  conv_k<<<NTOK, 256, 0, stream>>>(gvb, scl, wf, wm, wco, yb);
  // 4) x1 = x + y @ down_w^T
  gemm256_k<EPI_RES><<<dim3(64, 4), 512, 0, stream>>>(yb, wb_dn, x, x1, NTOK, 1024, 1024);
  // 5) h2 = rmsnorm(x1, ln2)
  rmsnorm_k<false><<<NTOK, 256, 0, stream>>>(x1, ln2w, nullptr, h2b, nullptr);
  // 6) gu = silu(h2 @ wg^T) * (h2 @ wu^T) via interleaved single GEMM [NTOK, 4096] bf16
  gemm256_k<EPI_SWIGLU_IL><<<dim3(64, 32), 512, 0, stream>>>(h2b, wb_il, nullptr, gub, NTOK, 8192, 1024);
  // 7) out = x1 + gu @ wo^T
  gemm256_k<EPI_RES><<<dim3(64, 4), 512, 0, stream>>>(gub, wb_wo, x1, (float*)d_out, NTOK, 1024, 4096);
}

// Round 9
// 767.445 us; speedup vs baseline: 1.3593x; 1.3593x over previous
//
#include <hip/hip_runtime.h>
#include <stdint.h>

// Problem dims (from reference)
#define D_MODEL 1024
#define D_FF    4096
#define NTOK    16384   // BATCH*SEQ = 4*4096
#define SEQ     4096

typedef __bf16 bf16x8 __attribute__((ext_vector_type(8)));
typedef float  f32x4  __attribute__((ext_vector_type(4)));

typedef __attribute__((address_space(1))) void gvoid;
typedef __attribute__((address_space(3))) void svoid;

__device__ __forceinline__ unsigned short f2bf(float f) {
  union { float f; uint32_t u; } v; v.f = f;
  uint32_t u = v.u;
  u += 0x7FFFu + ((u >> 16) & 1u);   // round-to-nearest-even
  return (unsigned short)(u >> 16);
}
__device__ __forceinline__ float bf2f(unsigned short h) {
  union { uint32_t u; float f; } v; v.u = ((uint32_t)h) << 16;
  return v.f;
}

// async global->LDS, 16B per lane (dest is wave-uniform base + lane*16)
__device__ __forceinline__ void gload16(const void* g, void* l) {
  __builtin_amdgcn_global_load_lds((gvoid*)g, (svoid*)l, 16, 0, 0);
}

__device__ __forceinline__ float fast_sigmoid(float x) {
  return __builtin_amdgcn_rcpf(1.f + __expf(-x));
}

// ---------------- fp32 -> bf16 weight conversion ----------------
__global__ __launch_bounds__(256) void cvt_k(const float* __restrict__ S,
                                             unsigned short* __restrict__ D, int n4) {
  int i = blockIdx.x * 256 + threadIdx.x;
  if (i < n4) {
    float4 f = reinterpret_cast<const float4*>(S)[i];
    ushort4 o;
    o.x = f2bf(f.x); o.y = f2bf(f.y); o.z = f2bf(f.z); o.w = f2bf(f.w);
    reinterpret_cast<ushort4*>(D)[i] = o;
  }
}

// interleave wg/wu rows: D row 2i = G[i], row 2i+1 = U[i]  (rows of length 1024)
__global__ __launch_bounds__(256) void cvt_il_k(const float* __restrict__ G,
                                                const float* __restrict__ U,
                                                unsigned short* __restrict__ D) {
  int i = blockIdx.x * 256 + threadIdx.x;      // ushort4 index; 8192*1024/4 total
  const int row = i >> 8;                      // 256 ushort4 per 1024-row
  const int c4  = i & 255;
  const float* src = ((row & 1) ? U : G) + (size_t)(row >> 1) * 1024 + c4 * 4;
  float4 f = *reinterpret_cast<const float4*>(src);
  ushort4 o;
  o.x = f2bf(f.x); o.y = f2bf(f.y); o.z = f2bf(f.z); o.w = f2bf(f.w);
  reinterpret_cast<ushort4*>(D)[i] = o;
}

// ---------------- RMSNorm (+ optional scale-gate softmax) ----------------
template<bool SG>
__global__ __launch_bounds__(256) void rmsnorm_k(
    const float* __restrict__ X, const float* __restrict__ W,
    const float* __restrict__ SGW,
    unsigned short* __restrict__ H, float* __restrict__ SCL)
{
  const int n = blockIdx.x;
  const int t = threadIdx.x;
  float4 x = reinterpret_cast<const float4*>(X + (size_t)n * D_MODEL)[t];
  float4 w = reinterpret_cast<const float4*>(W)[t];
  float4 hw;
  hw.x = x.x * w.x; hw.y = x.y * w.y; hw.z = x.z * w.z; hw.w = x.w * w.w;
  float ss = x.x*x.x + x.y*x.y + x.z*x.z + x.w*x.w;
  float p0 = 0.f, p1 = 0.f, p2 = 0.f;
  if (SG) {
    float4 s0 = reinterpret_cast<const float4*>(SGW)[t];
    float4 s1 = reinterpret_cast<const float4*>(SGW + D_MODEL)[t];
    float4 s2 = reinterpret_cast<const float4*>(SGW + 2 * D_MODEL)[t];
    p0 = hw.x*s0.x + hw.y*s0.y + hw.z*s0.z + hw.w*s0.w;
    p1 = hw.x*s1.x + hw.y*s1.y + hw.z*s1.z + hw.w*s1.w;
    p2 = hw.x*s2.x + hw.y*s2.y + hw.z*s2.z + hw.w*s2.w;
  }
  #pragma unroll
  for (int off = 32; off > 0; off >>= 1) {
    ss += __shfl_xor(ss, off);
    if (SG) {
      p0 += __shfl_xor(p0, off);
      p1 += __shfl_xor(p1, off);
      p2 += __shfl_xor(p2, off);
    }
  }
  __shared__ float red[4][4];
  const int wid = t >> 6;
  if ((t & 63) == 0) { red[wid][0] = ss; red[wid][1] = p0; red[wid][2] = p1; red[wid][3] = p2; }
  __syncthreads();
  ss = red[0][0] + red[1][0] + red[2][0] + red[3][0];
  const float r = rsqrtf(ss * (1.0f / D_MODEL) + 1e-6f);
  ushort4 h4;
  h4.x = f2bf(hw.x * r); h4.y = f2bf(hw.y * r); h4.z = f2bf(hw.z * r); h4.w = f2bf(hw.w * r);
  reinterpret_cast<ushort4*>(H + (size_t)n * D_MODEL)[t] = h4;
  if (SG && t == 0) {
    float l0 = (red[0][1] + red[1][1] + red[2][1] + red[3][1]) * r;
    float l1 = (red[0][2] + red[1][2] + red[2][2] + red[3][2]) * r;
    float l2 = (red[0][3] + red[1][3] + red[2][3] + red[3][3]) * r;
    float mx = fmaxf(l0, fmaxf(l1, l2));
    float e0 = expf(l0 - mx), e1 = expf(l1 - mx), e2 = expf(l2 - mx);
    float inv = 1.f / (e0 + e1 + e2);
    SCL[n * 3 + 0] = e0 * inv; SCL[n * 3 + 1] = e1 * inv; SCL[n * 3 + 2] = e2 * inv;
  }
}

// ---------------- multi-scale causal depthwise conv + gate mix ----------------
__global__ __launch_bounds__(256) void conv_k(
    const unsigned short* __restrict__ GV,   // [NTOK, 2048] bf16: gate | val
    const float* __restrict__ SCL,           // [NTOK, 3]
    const float* __restrict__ W3, const float* __restrict__ W5, const float* __restrict__ W7,
    unsigned short* __restrict__ Y)          // [NTOK, 1024] bf16
{
  const int n = blockIdx.x;
  const int t = threadIdx.x;
  const int d0 = t * 4;
  const int s = n & (SEQ - 1);
  const unsigned short* vbase = GV + (size_t)n * (2 * D_MODEL) + D_MODEL + d0;
  float v[7][4];
  #pragma unroll
  for (int j = 0; j < 7; ++j) {
    const int tap = 6 - j;
    if (tap <= s) {
      ushort4 u = *reinterpret_cast<const ushort4*>(vbase - (size_t)tap * (2 * D_MODEL));
      v[j][0] = bf2f(u.x); v[j][1] = bf2f(u.y); v[j][2] = bf2f(u.z); v[j][3] = bf2f(u.w);
    } else {
      v[j][0] = 0.f; v[j][1] = 0.f; v[j][2] = 0.f; v[j][3] = 0.f;
    }
  }
  ushort4 gb = *reinterpret_cast<const ushort4*>(GV + (size_t)n * (2 * D_MODEL) + d0);
  float gf[4] = { bf2f(gb.x), bf2f(gb.y), bf2f(gb.z), bf2f(gb.w) };
  const float sc0 = SCL[n * 3 + 0], sc1 = SCL[n * 3 + 1], sc2 = SCL[n * 3 + 2];
  ushort4 out;
  unsigned short o[4];
  #pragma unroll
  for (int i = 0; i < 4; ++i) {
    const int d = d0 + i;
    float c3 = W3[d*3+0]*v[4][i] + W3[d*3+1]*v[5][i] + W3[d*3+2]*v[6][i];
    float c5 = W5[d*5+0]*v[2][i] + W5[d*5+1]*v[3][i] + W5[d*5+2]*v[4][i]
             + W5[d*5+3]*v[5][i] + W5[d*5+4]*v[6][i];
    float c7 = 0.f;
    #pragma unroll
    for (int j = 0; j < 7; ++j) c7 += W7[d*7+j] * v[j][i];
    const float g = fast_sigmoid(gf[i]);
    o[i] = f2bf((sc0 * c3 + sc1 * c5 + sc2 * c7) * g);
  }
  out.x = o[0]; out.y = o[1]; out.z = o[2]; out.w = o[3];
  reinterpret_cast<ushort4*>(Y + (size_t)n * D_MODEL)[t] = out;
}

// ---------------- 256x256 8-phase BT GEMM: C[M,N] = A[M,K] * B[N,K]^T ----------------
// r9 — ERRATA from r7/r8: region A-H(h) is the wm-HALF (H0 = block rows
// 0-127 for wm=0 waves, H1 = rows 128-255 for wm=1). AQ0/AQ1 read the
// first/second 8KB WITHIN the same wm region, so EVERY wave reads its A
// region at BOTH pi0 and pi2. r7/r8 restaged A-H0 at pi1 -> overwrote data
// one phase before the pi2 reads (deterministic corruption). Fix: restage
// BOTH A halves at pi3/pi7 (after pi2/pi6 reads complete at the phase-end
// barrier). Also dropped the pi3 B0 re-read (b0 regs unclobbered with the
// split b0/b1 sets) -> 24 reads/slot, per-phase {12,4,8,0}.
// Stage map / iter: pi0 B(t+1,0); pi2 B(t+2,1); pi3 A(t+2,0)+A(t+2,1);
//                   pi4 B(t+2,0); pi6 B(t+3,1); pi7 A(t+3,0)+A(t+3,1).
// vmcnt(6) accounting (re-derived): steady-state entry queue = 6
// {B(t+1,1), A(t+1,0), A(t+1,1)}; pi3-END vmcnt(6) forces oldest 8 = all of
// tile t+1 slot1; pi7-END forces all of tile t+2 slot0. Prologue produces
// exactly the entry condition; peeled tail drains vmcnt(0) at slot boundary.
// Region lifetimes: A: read pi0+pi2, staged pi3 (1 barrier after pi2) OK;
// B-H1: read pi1, staged pi2 OK; B-H0: read pi0 (+consumed pi3 from regs),
// staged pi4 OK. All >=1 full barrier between last read and restage.
// LDS layout: slot s (s<<16) | A wm-half h (h<<14) | B at 32768 + (h<<14);
// row r: r*128 B; 16B chunk c holds global chunk c^(r&7) (pre-swizzled src).

#define EPI_BF16      0
#define EPI_RES       1
#define EPI_SWIGLU_IL 2

#define STAGE_A(tt, h) do { if ((tt) < nt) { \
    char* d_ = dstBase + (((tt)&1) << 16) + ((h) << 14); \
    const unsigned short* s_ = aSrc + (size_t)((h)*128) * K + (tt)*64; \
    gload16(s_, d_); gload16(s_ + (size_t)64 * K, d_ + 8192); } } while(0)

#define STAGE_B(tt, h) do { if ((tt) < nt) { \
    char* d_ = dstBase + (((tt)&1) << 16) + 32768 + ((h) << 14); \
    const unsigned short* s_ = bSrc + (size_t)((h)*32) * K + (tt)*64; \
    gload16(s_, d_); gload16(s_ + (size_t)128 * K, d_ + 8192); } } while(0)

#define STAGE_A2(tt) do { STAGE_A(tt, 0); STAGE_A(tt, 1); } while(0)

// raw ds_read_b128: base VGPR + literal offset
#define DSR(dst, base, IMM) \
  asm volatile("ds_read_b128 %0, %1 offset:" #IMM : "=v"(dst) : "v"(base))

#define LOAD_AQ0(S) do { \
  DSR(aq[0][0], aA##S##k0, 0);    DSR(aq[0][1], aA##S##k1, 0); \
  DSR(aq[1][0], aA##S##k0, 2048); DSR(aq[1][1], aA##S##k1, 2048); \
  DSR(aq[2][0], aA##S##k0, 4096); DSR(aq[2][1], aA##S##k1, 4096); \
  DSR(aq[3][0], aA##S##k0, 6144); DSR(aq[3][1], aA##S##k1, 6144); } while(0)

#define LOAD_AQ1(S) do { \
  DSR(aq[0][0], aA##S##k0, 8192);  DSR(aq[0][1], aA##S##k1, 8192); \
  DSR(aq[1][0], aA##S##k0, 10240); DSR(aq[1][1], aA##S##k1, 10240); \
  DSR(aq[2][0], aA##S##k0, 12288); DSR(aq[2][1], aA##S##k1, 12288); \
  DSR(aq[3][0], aA##S##k0, 14336); DSR(aq[3][1], aA##S##k1, 14336); } while(0)

#define LOAD_B_H0(S) do { \
  DSR(b0[0][0], bB##S##k0, 0);    DSR(b0[0][1], bB##S##k1, 0); \
  DSR(b0[1][0], bB##S##k0, 2048); DSR(b0[1][1], bB##S##k1, 2048); } while(0)

#define LOAD_B_H1(S) do { \
  DSR(b1[0][0], bB##S##k0, 16384); DSR(b1[0][1], bB##S##k1, 16384); \
  DSR(b1[1][0], bB##S##k0, 18432); DSR(b1[1][1], bB##S##k1, 18432); } while(0)

#define MMAQ(BR, MQ, NQ) do { \
  _Pragma("unroll") for (int f_ = 0; f_ < 4; ++f_) \
  _Pragma("unroll") for (int e_ = 0; e_ < 2; ++e_) { \
    acc[(MQ)*4+f_][(NQ)*2+e_] = __builtin_amdgcn_mfma_f32_16x16x32_bf16( \
        aq[f_][0], BR[e_][0], acc[(MQ)*4+f_][(NQ)*2+e_], 0, 0, 0); \
    acc[(MQ)*4+f_][(NQ)*2+e_] = __builtin_amdgcn_mfma_f32_16x16x32_bf16( \
        aq[f_][1], BR[e_][1], acc[(MQ)*4+f_][(NQ)*2+e_], 0, 0, 0); \
  } } while(0)

// throttle on 12-read phases (m201 pattern): let 8 drain later
#define THROTTLE8 asm volatile("s_waitcnt lgkmcnt(8)" ::: "memory")

#define PH_MID() \
  __builtin_amdgcn_s_barrier(); \
  asm volatile("s_waitcnt lgkmcnt(0)" ::: "memory"); \
  __builtin_amdgcn_sched_barrier(0); \
  __builtin_amdgcn_s_setprio(1)

#define PHASE_END() \
  __builtin_amdgcn_s_setprio(0); \
  __builtin_amdgcn_s_barrier()

#define PHASE_END_VM() \
  __builtin_amdgcn_s_setprio(0); \
  asm volatile("s_waitcnt vmcnt(6)" ::: "memory"); \
  __builtin_amdgcn_s_barrier()

#define PHASE_END_VM0() \
  __builtin_amdgcn_s_setprio(0); \
  asm volatile("s_waitcnt vmcnt(0)" ::: "memory"); \
  __builtin_amdgcn_s_barrier()

template<int EPI>
__global__ __launch_bounds__(512, 2) void gemm256_k(
    const unsigned short* __restrict__ A,
    const unsigned short* __restrict__ B0g,
    const float* __restrict__ RES,
    void* __restrict__ OUT,
    int M, int N, int K)
{
  __shared__ uint4 lds4[8192];   // 128 KB, LDS offset 0
  char* lbase = (char*)lds4;

  const int tid  = threadIdx.x;
  const int lane = tid & 63;
  const int wid  = tid >> 6;
  const int wm   = wid >> 2;        // 0..1
  const int wn   = wid & 3;         // 0..3
  const int l15 = lane & 15, l4 = lane >> 4, l7 = lane & 7;
  const int m0 = blockIdx.x * 256;
  const int n0 = blockIdx.y * 256;
  const int nt = K >> 6;            // always even, >= 16 here

  // staging: thread covers local row r0=tid>>3 (+64 for 2nd load), chunk slot
  // tid&7 which must hold global chunk (tid&7)^(r0&7)  (pre-swizzled source).
  const int r0 = tid >> 3;
  const int kc = (tid & 7) ^ (r0 & 7);
  const unsigned short* aSrc = A + (size_t)(m0 + r0) * K + kc * 8;
  const unsigned short* bSrc = B0g + (size_t)(n0 + (r0 >> 5) * 64 + (r0 & 31)) * K + kc * 8;
  char* dstBase = lbase + tid * 16;

  // fragment-read base addresses (raw LDS byte offsets; object at offset 0)
  const unsigned colswz = (unsigned)((l4 ^ l7) << 4);
  const unsigned aA0k0 = (unsigned)((wm << 14) + l15 * 128) + colswz;
  const unsigned aA0k1 = aA0k0 ^ 0x40u;        // kk=1: chunk (4+l4)^l7 = (l4^l7)^4
  const unsigned aA1k0 = aA0k0 + 65536u;
  const unsigned aA1k1 = aA0k1 + 65536u;
  const unsigned bB0k0 = (unsigned)(32768 + (wn * 32 + l15) * 128) + colswz;
  const unsigned bB0k1 = bB0k0 ^ 0x40u;
  const unsigned bB1k0 = bB0k0 + 65536u;
  const unsigned bB1k1 = bB0k1 + 65536u;

  f32x4 acc[8][4];
  #pragma unroll
  for (int i = 0; i < 8; ++i)
    #pragma unroll
    for (int j = 0; j < 4; ++j)
      #pragma unroll
      for (int r = 0; r < 4; ++r) acc[i][j][r] = 0.f;

  bf16x8 aq[4][2], b0[2][2], b1[2][2];

  // prologue: t0 fully + t1.{A0,A1,B1}; t1.B0 comes at pi0 of iter 0.
  // After vmcnt(6): tile0 slot0 resident; outstanding = {A(1,0),A(1,1),B(1,1)}
  // = exactly the steady-state entry condition.
  STAGE_A(0, 0); STAGE_A(0, 1); STAGE_B(0, 0); STAGE_B(0, 1);
  STAGE_A(1, 0); STAGE_A(1, 1); STAGE_B(1, 1);
  asm volatile("s_waitcnt vmcnt(6)" ::: "memory");
  __builtin_amdgcn_s_barrier();

  // -------- main loop: all t with t+2 < nt (full prefetch depth) --------
  for (int t = 0; t + 2 < nt; t += 2) {
    // pi0: tile t (slot0) — AQ0 + B0 (12 reads), quadrant (0,0)
    LOAD_AQ0(0); LOAD_B_H0(0);
    STAGE_B(t + 1, 0);
    THROTTLE8;
    PH_MID(); MMAQ(b0, 0, 0); PHASE_END();
    // pi1: B1 (4 reads), quadrant (0,1) — NO stage (A region still unread half)
    LOAD_B_H1(0);
    PH_MID(); MMAQ(b1, 0, 1); PHASE_END();
    // pi2: AQ1 (8 reads), quadrant (1,1) — stage B1 (B-H1 read finished pi1)
    LOAD_AQ1(0);
    STAGE_B(t + 2, 1);
    PH_MID(); MMAQ(b1, 1, 1); PHASE_END();
    // pi3: quadrant (1,0) from regs — stage BOTH A halves (A reads done pi2)
    STAGE_A2(t + 2);
    PH_MID(); MMAQ(b0, 1, 0); PHASE_END_VM();
    // pi4: tile t+1 (slot1)
    LOAD_AQ0(1); LOAD_B_H0(1);
    STAGE_B(t + 2, 0);
    THROTTLE8;
    PH_MID(); MMAQ(b0, 0, 0); PHASE_END();
    // pi5
    LOAD_B_H1(1);
    PH_MID(); MMAQ(b1, 0, 1); PHASE_END();
    // pi6 — stage B1 of t+3 (slot1 B-H1 read finished pi5)
    LOAD_AQ1(1);
    STAGE_B(t + 3, 1);
    PH_MID(); MMAQ(b1, 1, 1); PHASE_END();
    // pi7 — stage both A halves of t+3 (slot1 A reads done pi6)
    STAGE_A2(t + 3);
    PH_MID(); MMAQ(b0, 1, 0); PHASE_END_VM();
  }

  // -------- peeled final iteration (t = nt-2): no beyond-range stages;
  // queue is shallow so drain with vmcnt(0) at the slot boundary --------
  {
    // pi0: tile nt-2 (slot0) — fully landed via previous iter's pi7 vmcnt(6)
    LOAD_AQ0(0); LOAD_B_H0(0);
    STAGE_B(nt - 1, 0);
    THROTTLE8;
    PH_MID(); MMAQ(b0, 0, 0); PHASE_END();
    // pi1
    LOAD_B_H1(0);
    PH_MID(); MMAQ(b1, 0, 1); PHASE_END();
    // pi2
    LOAD_AQ1(0);
    PH_MID(); MMAQ(b1, 1, 1); PHASE_END();
    // pi3 — drain everything so tile nt-1 is fully resident before pi4
    PH_MID(); MMAQ(b0, 1, 0); PHASE_END_VM0();
    // pi4: tile nt-1 (slot1)
    LOAD_AQ0(1); LOAD_B_H0(1);
    THROTTLE8;
    PH_MID(); MMAQ(b0, 0, 0); PHASE_END();
    // pi5
    LOAD_B_H1(1);
    PH_MID(); MMAQ(b1, 0, 1); PHASE_END();
    // pi6
    LOAD_AQ1(1);
    PH_MID(); MMAQ(b1, 1, 1); PHASE_END();
    // pi7
    PH_MID(); MMAQ(b0, 1, 0); PHASE_END();
  }

  // keep LDS stores observable (never taken; M>0 always) — prevents DCE of
  // global_load_lds since no compiler-visible LDS reads remain.
  if (M < -1) ((float*)OUT)[tid] = ((float*)lds4)[tid];

  // epilogue: C/D fragment layout col=lane&15, row=(lane>>4)*4+rr
  const int cr = (lane >> 4) * 4;
  const int cc = lane & 15;
  #pragma unroll
  for (int F = 0; F < 8; ++F)
    #pragma unroll
    for (int E = 0; E < 4; ++E)
      #pragma unroll
      for (int rr = 0; rr < 4; ++rr) {
        const int grow = m0 + wm * 128 + (F >> 2) * 64 + (F & 3) * 16 + cr + rr;
        const int gcol = n0 + wn * 64 + (E >> 1) * 32 + (E & 1) * 16 + cc;
        const float v = acc[F][E][rr];
        if (EPI == EPI_BF16) {
          ((unsigned short*)OUT)[(size_t)grow * N + gcol] = f2bf(v);
        } else if (EPI == EPI_RES) {
          const size_t idx = (size_t)grow * N + gcol;
          ((float*)OUT)[idx] = RES[idx] + v;
        } else {  // EPI_SWIGLU_IL: even cc holds g, odd cc holds u for ff=gcol>>1
          const float pv = __shfl_xor(v, 1);
          const float g = (cc & 1) ? pv : v;
          const float u = (cc & 1) ? v : pv;
          const float o = g * fast_sigmoid(g) * u;
          unsigned int ob = f2bf(o);
          const unsigned int o2 = __shfl_xor((int)ob, 2);  // lane 4j gets ff+1's value
          if ((cc & 3) == 0) {
            const int ff = gcol >> 1;                      // even ff
            *reinterpret_cast<unsigned int*>(
                &((unsigned short*)OUT)[(size_t)grow * (D_FF) + ff]) = ob | (o2 << 16);
          }
        }
      }
}

// ---------------- launch ----------------
extern "C" void kernel_launch(void* const* d_in, const int* in_sizes, int n_in,
                              void* d_out, int out_size, void* d_ws, size_t ws_size,
                              hipStream_t stream)
{
  const float* x    = (const float*)d_in[0];
  const float* ln1w = (const float*)d_in[1];
  const float* ln2w = (const float*)d_in[2];
  const float* wf   = (const float*)d_in[3];
  const float* wm   = (const float*)d_in[4];
  const float* wco  = (const float*)d_in[5];
  const float* sgw  = (const float*)d_in[6];
  const float* upw  = (const float*)d_in[7];   // [2048,1024]
  const float* dnw  = (const float*)d_in[8];   // [1024,1024]
  const float* wg   = (const float*)d_in[9];   // [4096,1024]
  const float* wu   = (const float*)d_in[10];  // [4096,1024]
  const float* wo   = (const float*)d_in[11];  // [1024,4096]

  char* ws = (char*)d_ws;
  size_t off = 0;
  auto alloc = [&](size_t bytes) -> void* {
    void* p = ws + off;
    off += (bytes + 255) & ~(size_t)255;
    return p;
  };
  unsigned short* wb_up = (unsigned short*)alloc((size_t)2048 * 1024 * 2);
  unsigned short* wb_dn = (unsigned short*)alloc((size_t)1024 * 1024 * 2);
  unsigned short* wb_il = (unsigned short*)alloc((size_t)8192 * 1024 * 2);  // interleaved wg/wu
  unsigned short* wb_wo = (unsigned short*)alloc((size_t)1024 * 4096 * 2);
  float*          scl   = (float*)alloc((size_t)NTOK * 3 * 4);
  unsigned short* h2b   = (unsigned short*)alloc((size_t)NTOK * D_MODEL * 2);
  // 128MB region: h | gv | y live before the SwiGLU GEMM; gu aliases all three afterwards
  char* big = (char*)alloc((size_t)NTOK * 4096 * 2);
  unsigned short* hb  = (unsigned short*)big;                                  // [NTOK,1024]
  unsigned short* gvb = (unsigned short*)(big + (size_t)NTOK * 1024 * 2);      // [NTOK,2048]
  unsigned short* yb  = (unsigned short*)(big + (size_t)NTOK * 3072 * 2);      // [NTOK,1024]
  unsigned short* gub = (unsigned short*)big;                                  // [NTOK,4096]
  float* x1 = (float*)d_out;  // x after first residual lives in d_out

  // weights -> bf16
  cvt_k<<<2048, 256, 0, stream>>>(upw, wb_up, 2048 * 1024 / 4);
  cvt_k<<<1024, 256, 0, stream>>>(dnw, wb_dn, 1024 * 1024 / 4);
  cvt_il_k<<<8192, 256, 0, stream>>>(wg, wu, wb_il);
  cvt_k<<<4096, 256, 0, stream>>>(wo, wb_wo, 1024 * 4096 / 4);

  // 1) h = rmsnorm(x, ln1); scale_w = softmax(h @ sg_w^T)
  rmsnorm_k<true><<<NTOK, 256, 0, stream>>>(x, ln1w, sgw, hb, scl);
  // 2) gv = h @ up_w^T  [NTOK, 2048] bf16
  gemm256_k<EPI_BF16><<<dim3(64, 8), 512, 0, stream>>>(hb, wb_up, nullptr, gvb, NTOK, 2048, 1024);
  // 3) y = (sum_k scale_k * conv_k(val)) * sigmoid(gate)
  conv_k<<<NTOK, 256, 0, stream>>>(gvb, scl, wf, wm, wco, yb);
  // 4) x1 = x + y @ down_w^T
  gemm256_k<EPI_RES><<<dim3(64, 4), 512, 0, stream>>>(yb, wb_dn, x, x1, NTOK, 1024, 1024);
  // 5) h2 = rmsnorm(x1, ln2)
  rmsnorm_k<false><<<NTOK, 256, 0, stream>>>(x1, ln2w, nullptr, h2b, nullptr);
  // 6) gu = silu(h2 @ wg^T) * (h2 @ wu^T) via interleaved single GEMM [NTOK, 4096] bf16
  gemm256_k<EPI_SWIGLU_IL><<<dim3(64, 32), 512, 0, stream>>>(h2b, wb_il, nullptr, gub, NTOK, 8192, 1024);
  // 7) out = x1 + gu @ wo^T
  gemm256_k<EPI_RES><<<dim3(64, 4), 512, 0, stream>>>(gub, wb_wo, x1, (float*)d_out, NTOK, 1024, 4096);
}

// Round 10
// 683.906 us; speedup vs baseline: 1.5254x; 1.1221x over previous
//
#include <hip/hip_runtime.h>
#include <stdint.h>

// Problem dims (from reference)
#define D_MODEL 1024
#define D_FF    4096
#define NTOK    16384   // BATCH*SEQ = 4*4096
#define SEQ     4096

typedef __bf16 bf16x8 __attribute__((ext_vector_type(8)));
typedef float  f32x4  __attribute__((ext_vector_type(4)));

typedef __attribute__((address_space(1))) void gvoid;
typedef __attribute__((address_space(3))) void svoid;

__device__ __forceinline__ unsigned short f2bf(float f) {
  union { float f; uint32_t u; } v; v.f = f;
  uint32_t u = v.u;
  u += 0x7FFFu + ((u >> 16) & 1u);   // round-to-nearest-even
  return (unsigned short)(u >> 16);
}
__device__ __forceinline__ float bf2f(unsigned short h) {
  union { uint32_t u; float f; } v; v.u = ((uint32_t)h) << 16;
  return v.f;
}

// async global->LDS, 16B per lane (dest is wave-uniform base + lane*16)
__device__ __forceinline__ void gload16(const void* g, void* l) {
  __builtin_amdgcn_global_load_lds((gvoid*)g, (svoid*)l, 16, 0, 0);
}

__device__ __forceinline__ float fast_sigmoid(float x) {
  return __builtin_amdgcn_rcpf(1.f + __expf(-x));
}

// ---------------- fp32 -> bf16 weight conversion ----------------
__global__ __launch_bounds__(256) void cvt_k(const float* __restrict__ S,
                                             unsigned short* __restrict__ D, int n4) {
  int i = blockIdx.x * 256 + threadIdx.x;
  if (i < n4) {
    float4 f = reinterpret_cast<const float4*>(S)[i];
    ushort4 o;
    o.x = f2bf(f.x); o.y = f2bf(f.y); o.z = f2bf(f.z); o.w = f2bf(f.w);
    reinterpret_cast<ushort4*>(D)[i] = o;
  }
}

// 16-row-group interleave of wg/wu: D rows [32g..32g+15] = G rows [16g..16g+15],
// D rows [32g+16..32g+31] = U rows [16g..16g+15]. In the GEMM fragment space
// this puts g and u for the SAME ff at the same lane in adjacent 16-col
// fragments (E even = g, E odd = u) -> shfl-free SwiGLU epilogue.
__global__ __launch_bounds__(256) void cvt_il_k(const float* __restrict__ G,
                                                const float* __restrict__ U,
                                                unsigned short* __restrict__ D) {
  int i = blockIdx.x * 256 + threadIdx.x;      // ushort4 index; 8192*1024/4 total
  const int row = i >> 8;                      // 256 ushort4 per 1024-row
  const int c4  = i & 255;
  const int gi = row >> 5, w = row & 31;
  const float* src = (w < 16 ? G + (size_t)(gi * 16 + w) * 1024
                             : U + (size_t)(gi * 16 + (w - 16)) * 1024) + c4 * 4;
  float4 f = *reinterpret_cast<const float4*>(src);
  ushort4 o;
  o.x = f2bf(f.x); o.y = f2bf(f.y); o.z = f2bf(f.z); o.w = f2bf(f.w);
  reinterpret_cast<ushort4*>(D)[i] = o;
}

// ---------------- RMSNorm (+ optional scale-gate softmax) ----------------
template<bool SG>
__global__ __launch_bounds__(256) void rmsnorm_k(
    const float* __restrict__ X, const float* __restrict__ W,
    const float* __restrict__ SGW,
    unsigned short* __restrict__ H, float* __restrict__ SCL)
{
  const int n = blockIdx.x;
  const int t = threadIdx.x;
  float4 x = reinterpret_cast<const float4*>(X + (size_t)n * D_MODEL)[t];
  float4 w = reinterpret_cast<const float4*>(W)[t];
  float4 hw;
  hw.x = x.x * w.x; hw.y = x.y * w.y; hw.z = x.z * w.z; hw.w = x.w * w.w;
  float ss = x.x*x.x + x.y*x.y + x.z*x.z + x.w*x.w;
  float p0 = 0.f, p1 = 0.f, p2 = 0.f;
  if (SG) {
    float4 s0 = reinterpret_cast<const float4*>(SGW)[t];
    float4 s1 = reinterpret_cast<const float4*>(SGW + D_MODEL)[t];
    float4 s2 = reinterpret_cast<const float4*>(SGW + 2 * D_MODEL)[t];
    p0 = hw.x*s0.x + hw.y*s0.y + hw.z*s0.z + hw.w*s0.w;
    p1 = hw.x*s1.x + hw.y*s1.y + hw.z*s1.z + hw.w*s1.w;
    p2 = hw.x*s2.x + hw.y*s2.y + hw.z*s2.z + hw.w*s2.w;
  }
  #pragma unroll
  for (int off = 32; off > 0; off >>= 1) {
    ss += __shfl_xor(ss, off);
    if (SG) {
      p0 += __shfl_xor(p0, off);
      p1 += __shfl_xor(p1, off);
      p2 += __shfl_xor(p2, off);
    }
  }
  __shared__ float red[4][4];
  const int wid = t >> 6;
  if ((t & 63) == 0) { red[wid][0] = ss; red[wid][1] = p0; red[wid][2] = p1; red[wid][3] = p2; }
  __syncthreads();
  ss = red[0][0] + red[1][0] + red[2][0] + red[3][0];
  const float r = rsqrtf(ss * (1.0f / D_MODEL) + 1e-6f);
  ushort4 h4;
  h4.x = f2bf(hw.x * r); h4.y = f2bf(hw.y * r); h4.z = f2bf(hw.z * r); h4.w = f2bf(hw.w * r);
  reinterpret_cast<ushort4*>(H + (size_t)n * D_MODEL)[t] = h4;
  if (SG && t == 0) {
    float l0 = (red[0][1] + red[1][1] + red[2][1] + red[3][1]) * r;
    float l1 = (red[0][2] + red[1][2] + red[2][2] + red[3][2]) * r;
    float l2 = (red[0][3] + red[1][3] + red[2][3] + red[3][3]) * r;
    float mx = fmaxf(l0, fmaxf(l1, l2));
    float e0 = expf(l0 - mx), e1 = expf(l1 - mx), e2 = expf(l2 - mx);
    float inv = 1.f / (e0 + e1 + e2);
    SCL[n * 3 + 0] = e0 * inv; SCL[n * 3 + 1] = e1 * inv; SCL[n * 3 + 2] = e2 * inv;
  }
}

// ---------------- multi-scale causal depthwise conv + gate mix ----------------
__global__ __launch_bounds__(256) void conv_k(
    const unsigned short* __restrict__ GV,   // [NTOK, 2048] bf16: gate | val
    const float* __restrict__ SCL,           // [NTOK, 3]
    const float* __restrict__ W3, const float* __restrict__ W5, const float* __restrict__ W7,
    unsigned short* __restrict__ Y)          // [NTOK, 1024] bf16
{
  const int n = blockIdx.x;
  const int t = threadIdx.x;
  const int d0 = t * 4;
  const int s = n & (SEQ - 1);
  const unsigned short* vbase = GV + (size_t)n * (2 * D_MODEL) + D_MODEL + d0;
  float v[7][4];
  #pragma unroll
  for (int j = 0; j < 7; ++j) {
    const int tap = 6 - j;
    if (tap <= s) {
      ushort4 u = *reinterpret_cast<const ushort4*>(vbase - (size_t)tap * (2 * D_MODEL));
      v[j][0] = bf2f(u.x); v[j][1] = bf2f(u.y); v[j][2] = bf2f(u.z); v[j][3] = bf2f(u.w);
    } else {
      v[j][0] = 0.f; v[j][1] = 0.f; v[j][2] = 0.f; v[j][3] = 0.f;
    }
  }
  ushort4 gb = *reinterpret_cast<const ushort4*>(GV + (size_t)n * (2 * D_MODEL) + d0);
  float gf[4] = { bf2f(gb.x), bf2f(gb.y), bf2f(gb.z), bf2f(gb.w) };
  const float sc0 = SCL[n * 3 + 0], sc1 = SCL[n * 3 + 1], sc2 = SCL[n * 3 + 2];
  ushort4 out;
  unsigned short o[4];
  #pragma unroll
  for (int i = 0; i < 4; ++i) {
    const int d = d0 + i;
    float c3 = W3[d*3+0]*v[4][i] + W3[d*3+1]*v[5][i] + W3[d*3+2]*v[6][i];
    float c5 = W5[d*5+0]*v[2][i] + W5[d*5+1]*v[3][i] + W5[d*5+2]*v[4][i]
             + W5[d*5+3]*v[5][i] + W5[d*5+4]*v[6][i];
    float c7 = 0.f;
    #pragma unroll
    for (int j = 0; j < 7; ++j) c7 += W7[d*7+j] * v[j][i];
    const float g = fast_sigmoid(gf[i]);
    o[i] = f2bf((sc0 * c3 + sc1 * c5 + sc2 * c7) * g);
  }
  out.x = o[0]; out.y = o[1]; out.z = o[2]; out.w = o[3];
  reinterpret_cast<ushort4*>(Y + (size_t)n * D_MODEL)[t] = out;
}

// ---------------- 256x256 BT GEMM, 2-phase/tile: C = A * B^T ----------------
// r10: merged 4 phases -> 2 per tile, ONE barrier per phase, intra-phase
// counted-lgkm gates so LDS drain overlaps MFMA:
//   P0(slot s, row0): issue B0(4),AQ0(8),B1(4); stage A(next-slot);
//     lgkm(4)->MMAQ(0,0) [B1 drains under it]; lgkm(0)->MMAQ(0,1); barrier.
//   P1(slot s, row1): issue AQ1a(4),AQ1b(4); stage B(slot-s tile+2);
//     lgkm(4)->half rows f0,1 of (1,1)+(1,0); lgkm(0)->rows f2,3; vmcnt(4); barrier.
// Correctness: a wave passes a phase-end barrier only after its lgkm(0),
// so the single end-barrier guarantees all waves' reads of a region are
// complete before any wave's next-phase restage (MID barrier was redundant).
// Stage map/iter: P0:A(t+1,*)->s1A(last read prev-P3); P1:B(t+2,*)->s0B(read P0);
//   P2:A(t+2,*)->s0A(read P1); P3:B(t+3,*)->s1B(read P2). All in-range (no guards).
// vmcnt(4) accounting: P1-end queue = [B(t+1) 4][A(t+1) 4][B(t+2) 4] -> forces
// tile t+1 slot1 before P2. P3-end queue = [B(t+2)][A(t+2)][B(t+3)] -> forces
// tile t+2 slot0 before next P0. Prologue: A(0),B(0) then B(1), vmcnt(4) ->
// exactly the steady-state entry (B(1) in flight). Final iter peeled:
// P1-end vmcnt(0) (queue only 8 there), no stages at P1/P2/P3.
// LDS: slot s (s<<16) | A wm-half h (h<<14) | B at 32768+(h<<14); row r: r*128B;
// 16B chunk c holds global chunk c^(r&7) (pre-swizzled source, XOR on read).
// XCD swizzle (bijective; all grids %8==0): consecutive same-XCD blocks share
// the 512KB B panel in that XCD's L2.

#define EPI_BF16      0
#define EPI_RES       1
#define EPI_SWIGLU_IL 2

#define STAGE_A(tt, h) do { \
    char* d_ = dstBase + (((tt)&1) << 16) + ((h) << 14); \
    const unsigned short* s_ = aSrc + (size_t)((h)*128) * K + (tt)*64; \
    gload16(s_, d_); gload16(s_ + (size_t)64 * K, d_ + 8192); } while(0)

#define STAGE_B(tt, h) do { \
    char* d_ = dstBase + (((tt)&1) << 16) + 32768 + ((h) << 14); \
    const unsigned short* s_ = bSrc + (size_t)((h)*32) * K + (tt)*64; \
    gload16(s_, d_); gload16(s_ + (size_t)128 * K, d_ + 8192); } while(0)

// raw ds_read_b128: base VGPR + literal offset
#define DSR(dst, base, IMM) \
  asm volatile("ds_read_b128 %0, %1 offset:" #IMM : "=v"(dst) : "v"(base))

#define RD_B0(S) do { \
  DSR(b0[0][0], bB##S##k0, 0);    DSR(b0[0][1], bB##S##k1, 0); \
  DSR(b0[1][0], bB##S##k0, 2048); DSR(b0[1][1], bB##S##k1, 2048); } while(0)

#define RD_B1(S) do { \
  DSR(b1[0][0], bB##S##k0, 16384); DSR(b1[0][1], bB##S##k1, 16384); \
  DSR(b1[1][0], bB##S##k0, 18432); DSR(b1[1][1], bB##S##k1, 18432); } while(0)

#define RD_AQ0(S) do { \
  DSR(aq[0][0], aA##S##k0, 0);    DSR(aq[0][1], aA##S##k1, 0); \
  DSR(aq[1][0], aA##S##k0, 2048); DSR(aq[1][1], aA##S##k1, 2048); \
  DSR(aq[2][0], aA##S##k0, 4096); DSR(aq[2][1], aA##S##k1, 4096); \
  DSR(aq[3][0], aA##S##k0, 6144); DSR(aq[3][1], aA##S##k1, 6144); } while(0)

#define RD_AQ1A(S) do { \
  DSR(aq[0][0], aA##S##k0, 8192);  DSR(aq[0][1], aA##S##k1, 8192); \
  DSR(aq[1][0], aA##S##k0, 10240); DSR(aq[1][1], aA##S##k1, 10240); } while(0)

#define RD_AQ1B(S) do { \
  DSR(aq[2][0], aA##S##k0, 12288); DSR(aq[2][1], aA##S##k1, 12288); \
  DSR(aq[3][0], aA##S##k0, 14336); DSR(aq[3][1], aA##S##k1, 14336); } while(0)

#define MMAQ(BR, MQ, NQ) do { \
  _Pragma("unroll") for (int f_ = 0; f_ < 4; ++f_) \
  _Pragma("unroll") for (int e_ = 0; e_ < 2; ++e_) { \
    acc[(MQ)*4+f_][(NQ)*2+e_] = __builtin_amdgcn_mfma_f32_16x16x32_bf16( \
        aq[f_][0], BR[e_][0], acc[(MQ)*4+f_][(NQ)*2+e_], 0, 0, 0); \
    acc[(MQ)*4+f_][(NQ)*2+e_] = __builtin_amdgcn_mfma_f32_16x16x32_bf16( \
        aq[f_][1], BR[e_][1], acc[(MQ)*4+f_][(NQ)*2+e_], 0, 0, 0); \
  } } while(0)

#define MMAQH(BR, MQ, NQ, F0) do { \
  _Pragma("unroll") for (int f_ = (F0); f_ < (F0) + 2; ++f_) \
  _Pragma("unroll") for (int e_ = 0; e_ < 2; ++e_) { \
    acc[(MQ)*4+f_][(NQ)*2+e_] = __builtin_amdgcn_mfma_f32_16x16x32_bf16( \
        aq[f_][0], BR[e_][0], acc[(MQ)*4+f_][(NQ)*2+e_], 0, 0, 0); \
    acc[(MQ)*4+f_][(NQ)*2+e_] = __builtin_amdgcn_mfma_f32_16x16x32_bf16( \
        aq[f_][1], BR[e_][1], acc[(MQ)*4+f_][(NQ)*2+e_], 0, 0, 0); \
  } } while(0)

#define GATE4 do { asm volatile("s_waitcnt lgkmcnt(4)" ::: "memory"); \
                   __builtin_amdgcn_sched_barrier(0); } while(0)
#define GATE0 do { asm volatile("s_waitcnt lgkmcnt(0)" ::: "memory"); \
                   __builtin_amdgcn_sched_barrier(0); } while(0)
#define VM4   asm volatile("s_waitcnt vmcnt(4)" ::: "memory")
#define VM0   asm volatile("s_waitcnt vmcnt(0)" ::: "memory")
#define BAR   __builtin_amdgcn_s_barrier()
#define PRIO1 __builtin_amdgcn_s_setprio(1)
#define PRIO0 __builtin_amdgcn_s_setprio(0)

template<int EPI>
__global__ __launch_bounds__(512, 2) void gemm256_k(
    const unsigned short* __restrict__ A,
    const unsigned short* __restrict__ B0g,
    const float* __restrict__ RES,
    void* __restrict__ OUT,
    int M, int N, int K)
{
  __shared__ uint4 lds4[8192];   // 128 KB, LDS offset 0
  char* lbase = (char*)lds4;

  const int tid  = threadIdx.x;
  const int lane = tid & 63;
  const int wid  = tid >> 6;
  const int wm   = wid >> 2;        // 0..1
  const int wn   = wid & 3;         // 0..3
  const int l15 = lane & 15, l4 = lane >> 4, l7 = lane & 7;

  // XCD-aware bijective block swizzle (nwg % 8 == 0 for all our grids)
  const int nbx = gridDim.x;
  const int id  = blockIdx.y * nbx + blockIdx.x;
  const int cpx = (nbx * gridDim.y) >> 3;
  const int swz = (id & 7) * cpx + (id >> 3);
  const int m0 = (swz % nbx) * 256;
  const int n0 = (swz / nbx) * 256;
  const int nt = K >> 6;            // even (16 or 64 here)

  // staging: thread covers local row r0=tid>>3 (+64 for 2nd load), chunk slot
  // tid&7 which must hold global chunk (tid&7)^(r0&7)  (pre-swizzled source).
  const int r0 = tid >> 3;
  const int kc = (tid & 7) ^ (r0 & 7);
  const unsigned short* aSrc = A + (size_t)(m0 + r0) * K + kc * 8;
  const unsigned short* bSrc = B0g + (size_t)(n0 + (r0 >> 5) * 64 + (r0 & 31)) * K + kc * 8;
  char* dstBase = lbase + tid * 16;

  // fragment-read base addresses (raw LDS byte offsets; object at offset 0)
  const unsigned colswz = (unsigned)((l4 ^ l7) << 4);
  const unsigned aA0k0 = (unsigned)((wm << 14) + l15 * 128) + colswz;
  const unsigned aA0k1 = aA0k0 ^ 0x40u;        // kk=1: chunk (4+l4)^l7 = (l4^l7)^4
  const unsigned aA1k0 = aA0k0 + 65536u;
  const unsigned aA1k1 = aA0k1 + 65536u;
  const unsigned bB0k0 = (unsigned)(32768 + (wn * 32 + l15) * 128) + colswz;
  const unsigned bB0k1 = bB0k0 ^ 0x40u;
  const unsigned bB1k0 = bB0k0 + 65536u;       // slot1 B base
  const unsigned bB1k1 = bB0k1 + 65536u;

  f32x4 acc[8][4];
  #pragma unroll
  for (int i = 0; i < 8; ++i)
    #pragma unroll
    for (int j = 0; j < 4; ++j)
      #pragma unroll
      for (int r = 0; r < 4; ++r) acc[i][j][r] = 0.f;

  bf16x8 aq[4][2], b0[2][2], b1[2][2];

  // prologue: tile0 (8 loads) then B(1,*) (4) -> vmcnt(4): tile0 resident,
  // B(1) may fly = steady-state entry condition.
  STAGE_A(0, 0); STAGE_A(0, 1); STAGE_B(0, 0); STAGE_B(0, 1);
  STAGE_B(1, 0); STAGE_B(1, 1);
  VM4;
  BAR;

  // -------- main loop (full prefetch depth) --------
  for (int t = 0; t + 2 < nt; t += 2) {
    // P0: slot0 row0
    RD_B0(0); RD_AQ0(0); RD_B1(0);
    STAGE_A(t + 1, 0); STAGE_A(t + 1, 1);
    GATE4; PRIO1; MMAQ(b0, 0, 0); PRIO0;
    GATE0; PRIO1; MMAQ(b1, 0, 1); PRIO0;
    BAR;
    // P1: slot0 row1
    RD_AQ1A(0); RD_AQ1B(0);
    STAGE_B(t + 2, 0); STAGE_B(t + 2, 1);
    GATE4; PRIO1; MMAQH(b1, 1, 1, 0); MMAQH(b0, 1, 0, 0); PRIO0;
    GATE0; PRIO1; MMAQH(b1, 1, 1, 2); MMAQH(b0, 1, 0, 2); PRIO0;
    VM4;
    BAR;
    // P2: slot1 row0
    RD_B0(1); RD_AQ0(1); RD_B1(1);
    STAGE_A(t + 2, 0); STAGE_A(t + 2, 1);
    GATE4; PRIO1; MMAQ(b0, 0, 0); PRIO0;
    GATE0; PRIO1; MMAQ(b1, 0, 1); PRIO0;
    BAR;
    // P3: slot1 row1
    RD_AQ1A(1); RD_AQ1B(1);
    STAGE_B(t + 3, 0); STAGE_B(t + 3, 1);
    GATE4; PRIO1; MMAQH(b1, 1, 1, 0); MMAQH(b0, 1, 0, 0); PRIO0;
    GATE0; PRIO1; MMAQH(b1, 1, 1, 2); MMAQH(b0, 1, 0, 2); PRIO0;
    VM4;
    BAR;
  }

  // -------- peeled final iteration (t = nt-2) --------
  {
    // P0: stages A(nt-1) (in range)
    RD_B0(0); RD_AQ0(0); RD_B1(0);
    STAGE_A(nt - 1, 0); STAGE_A(nt - 1, 1);
    GATE4; PRIO1; MMAQ(b0, 0, 0); PRIO0;
    GATE0; PRIO1; MMAQ(b1, 0, 1); PRIO0;
    BAR;
    // P1: no stages; queue is only 8 deep -> drain fully so slot1 resident
    RD_AQ1A(0); RD_AQ1B(0);
    GATE4; PRIO1; MMAQH(b1, 1, 1, 0); MMAQH(b0, 1, 0, 0); PRIO0;
    GATE0; PRIO1; MMAQH(b1, 1, 1, 2); MMAQH(b0, 1, 0, 2); PRIO0;
    VM0;
    BAR;
    // P2
    RD_B0(1); RD_AQ0(1); RD_B1(1);
    GATE4; PRIO1; MMAQ(b0, 0, 0); PRIO0;
    GATE0; PRIO1; MMAQ(b1, 0, 1); PRIO0;
    BAR;
    // P3
    RD_AQ1A(1); RD_AQ1B(1);
    GATE4; PRIO1; MMAQH(b1, 1, 1, 0); MMAQH(b0, 1, 0, 0); PRIO0;
    GATE0; PRIO1; MMAQH(b1, 1, 1, 2); MMAQH(b0, 1, 0, 2); PRIO0;
    BAR;
  }

  // keep LDS stores observable (never taken; M>0 always) — prevents DCE of
  // global_load_lds since no compiler-visible LDS reads remain.
  if (M < -1) ((float*)OUT)[tid] = ((float*)lds4)[tid];

  // epilogue: C/D fragment layout col=lane&15, row=(lane>>4)*4+rr
  const int cr = (lane >> 4) * 4;
  const int cc = lane & 15;
  if (EPI == EPI_SWIGLU_IL) {
    // 16-group interleave: E even holds g, E odd holds u for the SAME
    // ff = (n0+wn*64)/2 + (E>>1)*16 + cc. No shfl needed.
    const int ffbase = (n0 + wn * 64) >> 1;
    #pragma unroll
    for (int F = 0; F < 8; ++F)
      #pragma unroll
      for (int p = 0; p < 2; ++p)
        #pragma unroll
        for (int rr = 0; rr < 4; ++rr) {
          const int grow = m0 + wm * 128 + (F >> 2) * 64 + (F & 3) * 16 + cr + rr;
          const float g = acc[F][2 * p][rr];
          const float u = acc[F][2 * p + 1][rr];
          const float o = g * fast_sigmoid(g) * u;
          ((unsigned short*)OUT)[(size_t)grow * D_FF + ffbase + p * 16 + cc] = f2bf(o);
        }
  } else {
    #pragma unroll
    for (int F = 0; F < 8; ++F)
      #pragma unroll
      for (int E = 0; E < 4; ++E)
        #pragma unroll
        for (int rr = 0; rr < 4; ++rr) {
          const int grow = m0 + wm * 128 + (F >> 2) * 64 + (F & 3) * 16 + cr + rr;
          const int gcol = n0 + wn * 64 + (E >> 1) * 32 + (E & 1) * 16 + cc;
          const float v = acc[F][E][rr];
          if (EPI == EPI_BF16) {
            ((unsigned short*)OUT)[(size_t)grow * N + gcol] = f2bf(v);
          } else {  // EPI_RES
            const size_t idx = (size_t)grow * N + gcol;
            ((float*)OUT)[idx] = RES[idx] + v;
          }
        }
  }
}

// ---------------- launch ----------------
extern "C" void kernel_launch(void* const* d_in, const int* in_sizes, int n_in,
                              void* d_out, int out_size, void* d_ws, size_t ws_size,
                              hipStream_t stream)
{
  const float* x    = (const float*)d_in[0];
  const float* ln1w = (const float*)d_in[1];
  const float* ln2w = (const float*)d_in[2];
  const float* wf   = (const float*)d_in[3];
  const float* wm   = (const float*)d_in[4];
  const float* wco  = (const float*)d_in[5];
  const float* sgw  = (const float*)d_in[6];
  const float* upw  = (const float*)d_in[7];   // [2048,1024]
  const float* dnw  = (const float*)d_in[8];   // [1024,1024]
  const float* wg   = (const float*)d_in[9];   // [4096,1024]
  const float* wu   = (const float*)d_in[10];  // [4096,1024]
  const float* wo   = (const float*)d_in[11];  // [1024,4096]

  char* ws = (char*)d_ws;
  size_t off = 0;
  auto alloc = [&](size_t bytes) -> void* {
    void* p = ws + off;
    off += (bytes + 255) & ~(size_t)255;
    return p;
  };
  unsigned short* wb_up = (unsigned short*)alloc((size_t)2048 * 1024 * 2);
  unsigned short* wb_dn = (unsigned short*)alloc((size_t)1024 * 1024 * 2);
  unsigned short* wb_il = (unsigned short*)alloc((size_t)8192 * 1024 * 2);  // interleaved wg/wu
  unsigned short* wb_wo = (unsigned short*)alloc((size_t)1024 * 4096 * 2);
  float*          scl   = (float*)alloc((size_t)NTOK * 3 * 4);
  unsigned short* h2b   = (unsigned short*)alloc((size_t)NTOK * D_MODEL * 2);
  // 128MB region: h | gv | y live before the SwiGLU GEMM; gu aliases all three afterwards
  char* big = (char*)alloc((size_t)NTOK * 4096 * 2);
  unsigned short* hb  = (unsigned short*)big;                                  // [NTOK,1024]
  unsigned short* gvb = (unsigned short*)(big + (size_t)NTOK * 1024 * 2);      // [NTOK,2048]
  unsigned short* yb  = (unsigned short*)(big + (size_t)NTOK * 3072 * 2);      // [NTOK,1024]
  unsigned short* gub = (unsigned short*)big;                                  // [NTOK,4096]
  float* x1 = (float*)d_out;  // x after first residual lives in d_out

  // weights -> bf16
  cvt_k<<<2048, 256, 0, stream>>>(upw, wb_up, 2048 * 1024 / 4);
  cvt_k<<<1024, 256, 0, stream>>>(dnw, wb_dn, 1024 * 1024 / 4);
  cvt_il_k<<<8192, 256, 0, stream>>>(wg, wu, wb_il);
  cvt_k<<<4096, 256, 0, stream>>>(wo, wb_wo, 1024 * 4096 / 4);

  // 1) h = rmsnorm(x, ln1); scale_w = softmax(h @ sg_w^T)
  rmsnorm_k<true><<<NTOK, 256, 0, stream>>>(x, ln1w, sgw, hb, scl);
  // 2) gv = h @ up_w^T  [NTOK, 2048] bf16
  gemm256_k<EPI_BF16><<<dim3(64, 8), 512, 0, stream>>>(hb, wb_up, nullptr, gvb, NTOK, 2048, 1024);
  // 3) y = (sum_k scale_k * conv_k(val)) * sigmoid(gate)
  conv_k<<<NTOK, 256, 0, stream>>>(gvb, scl, wf, wm, wco, yb);
  // 4) x1 = x + y @ down_w^T
  gemm256_k<EPI_RES><<<dim3(64, 4), 512, 0, stream>>>(yb, wb_dn, x, x1, NTOK, 1024, 1024);
  // 5) h2 = rmsnorm(x1, ln2)
  rmsnorm_k<false><<<NTOK, 256, 0, stream>>>(x1, ln2w, nullptr, h2b, nullptr);
  // 6) gu = silu(h2 @ wg^T) * (h2 @ wu^T) via 16-group interleaved GEMM [NTOK, 4096] bf16
  gemm256_k<EPI_SWIGLU_IL><<<dim3(64, 32), 512, 0, stream>>>(h2b, wb_il, nullptr, gub, NTOK, 8192, 1024);
  // 7) out = x1 + gu @ wo^T
  gemm256_k<EPI_RES><<<dim3(64, 4), 512, 0, stream>>>(gub, wb_wo, x1, (float*)d_out, NTOK, 1024, 4096);
}

// Round 11
// 659.288 us; speedup vs baseline: 1.5823x; 1.0373x over previous
//
#include <hip/hip_runtime.h>
#include <stdint.h>

// Problem dims (from reference)
#define D_MODEL 1024
#define D_FF    4096
#define NTOK    16384   // BATCH*SEQ = 4*4096
#define SEQ     4096

typedef __bf16 bf16x8 __attribute__((ext_vector_type(8)));
typedef float  f32x4  __attribute__((ext_vector_type(4)));

typedef __attribute__((address_space(1))) void gvoid;
typedef __attribute__((address_space(3))) void svoid;

__device__ __forceinline__ unsigned short f2bf(float f) {
  union { float f; uint32_t u; } v; v.f = f;
  uint32_t u = v.u;
  u += 0x7FFFu + ((u >> 16) & 1u);   // round-to-nearest-even
  return (unsigned short)(u >> 16);
}
__device__ __forceinline__ float bf2f(unsigned short h) {
  union { uint32_t u; float f; } v; v.u = ((uint32_t)h) << 16;
  return v.f;
}

// async global->LDS, 16B per lane (dest is wave-uniform base + lane*16)
__device__ __forceinline__ void gload16(const void* g, void* l) {
  __builtin_amdgcn_global_load_lds((gvoid*)g, (svoid*)l, 16, 0, 0);
}

__device__ __forceinline__ float fast_sigmoid(float x) {
  return __builtin_amdgcn_rcpf(1.f + __expf(-x));
}

// ---------------- fused fp32 -> bf16 weight conversion (all weights, 1 launch) ----------------
// Segments (ushort4 index space): up [0,524288) | dn [524288,786432) |
// wo [786432,1835008) | il(wg/wu 16-row-group interleave) [1835008,3932160)
__global__ __launch_bounds__(256) void cvt_all_k(
    const float* __restrict__ up, const float* __restrict__ dn,
    const float* __restrict__ wo, const float* __restrict__ wg,
    const float* __restrict__ wu,
    unsigned short* __restrict__ d_up, unsigned short* __restrict__ d_dn,
    unsigned short* __restrict__ d_wo, unsigned short* __restrict__ d_il)
{
  const int i = blockIdx.x * 256 + threadIdx.x;
  const float* src;
  unsigned short* dst;
  if (i < 524288) {
    src = up + (size_t)i * 4;            dst = d_up + (size_t)i * 4;
  } else if (i < 786432) {
    const int j = i - 524288;
    src = dn + (size_t)j * 4;            dst = d_dn + (size_t)j * 4;
  } else if (i < 1835008) {
    const int j = i - 786432;
    src = wo + (size_t)j * 4;            dst = d_wo + (size_t)j * 4;
  } else {
    // 16-row-group interleave: D rows [32g..32g+15]=G[16g..16g+15],
    // [32g+16..32g+31]=U[16g..16g+15] -> g,u for same ff land in adjacent
    // 16-col fragments (E even = g, E odd = u): shfl-free SwiGLU epilogue.
    const int j = i - 1835008;
    const int row = j >> 8, c4 = j & 255;
    const int gi = row >> 5, w = row & 31;
    src = (w < 16 ? wg + (size_t)(gi * 16 + w) * 1024
                  : wu + (size_t)(gi * 16 + (w - 16)) * 1024) + c4 * 4;
    dst = d_il + (size_t)j * 4;
  }
  float4 f = *reinterpret_cast<const float4*>(src);
  ushort4 o;
  o.x = f2bf(f.x); o.y = f2bf(f.y); o.z = f2bf(f.z); o.w = f2bf(f.w);
  *reinterpret_cast<ushort4*>(dst) = o;
}

// ---------------- RMSNorm (+ optional scale-gate softmax) ----------------
template<bool SG>
__global__ __launch_bounds__(256) void rmsnorm_k(
    const float* __restrict__ X, const float* __restrict__ W,
    const float* __restrict__ SGW,
    unsigned short* __restrict__ H, float* __restrict__ SCL)
{
  const int n = blockIdx.x;
  const int t = threadIdx.x;
  float4 x = reinterpret_cast<const float4*>(X + (size_t)n * D_MODEL)[t];
  float4 w = reinterpret_cast<const float4*>(W)[t];
  float4 hw;
  hw.x = x.x * w.x; hw.y = x.y * w.y; hw.z = x.z * w.z; hw.w = x.w * w.w;
  float ss = x.x*x.x + x.y*x.y + x.z*x.z + x.w*x.w;
  float p0 = 0.f, p1 = 0.f, p2 = 0.f;
  if (SG) {
    float4 s0 = reinterpret_cast<const float4*>(SGW)[t];
    float4 s1 = reinterpret_cast<const float4*>(SGW + D_MODEL)[t];
    float4 s2 = reinterpret_cast<const float4*>(SGW + 2 * D_MODEL)[t];
    p0 = hw.x*s0.x + hw.y*s0.y + hw.z*s0.z + hw.w*s0.w;
    p1 = hw.x*s1.x + hw.y*s1.y + hw.z*s1.z + hw.w*s1.w;
    p2 = hw.x*s2.x + hw.y*s2.y + hw.z*s2.z + hw.w*s2.w;
  }
  #pragma unroll
  for (int off = 32; off > 0; off >>= 1) {
    ss += __shfl_xor(ss, off);
    if (SG) {
      p0 += __shfl_xor(p0, off);
      p1 += __shfl_xor(p1, off);
      p2 += __shfl_xor(p2, off);
    }
  }
  __shared__ float red[4][4];
  const int wid = t >> 6;
  if ((t & 63) == 0) { red[wid][0] = ss; red[wid][1] = p0; red[wid][2] = p1; red[wid][3] = p2; }
  __syncthreads();
  ss = red[0][0] + red[1][0] + red[2][0] + red[3][0];
  const float r = rsqrtf(ss * (1.0f / D_MODEL) + 1e-6f);
  ushort4 h4;
  h4.x = f2bf(hw.x * r); h4.y = f2bf(hw.y * r); h4.z = f2bf(hw.z * r); h4.w = f2bf(hw.w * r);
  reinterpret_cast<ushort4*>(H + (size_t)n * D_MODEL)[t] = h4;
  if (SG && t == 0) {
    float l0 = (red[0][1] + red[1][1] + red[2][1] + red[3][1]) * r;
    float l1 = (red[0][2] + red[1][2] + red[2][2] + red[3][2]) * r;
    float l2 = (red[0][3] + red[1][3] + red[2][3] + red[3][3]) * r;
    float mx = fmaxf(l0, fmaxf(l1, l2));
    float e0 = expf(l0 - mx), e1 = expf(l1 - mx), e2 = expf(l2 - mx);
    float inv = 1.f / (e0 + e1 + e2);
    SCL[n * 3 + 0] = e0 * inv; SCL[n * 3 + 1] = e1 * inv; SCL[n * 3 + 2] = e2 * inv;
  }
}

// ---------------- multi-scale causal depthwise conv + gate mix ----------------
__global__ __launch_bounds__(256) void conv_k(
    const unsigned short* __restrict__ GV,   // [NTOK, 2048] bf16: gate | val
    const float* __restrict__ SCL,           // [NTOK, 3]
    const float* __restrict__ W3, const float* __restrict__ W5, const float* __restrict__ W7,
    unsigned short* __restrict__ Y)          // [NTOK, 1024] bf16
{
  const int n = blockIdx.x;
  const int t = threadIdx.x;
  const int d0 = t * 4;
  const int s = n & (SEQ - 1);
  const unsigned short* vbase = GV + (size_t)n * (2 * D_MODEL) + D_MODEL + d0;
  float v[7][4];
  #pragma unroll
  for (int j = 0; j < 7; ++j) {
    const int tap = 6 - j;
    if (tap <= s) {
      ushort4 u = *reinterpret_cast<const ushort4*>(vbase - (size_t)tap * (2 * D_MODEL));
      v[j][0] = bf2f(u.x); v[j][1] = bf2f(u.y); v[j][2] = bf2f(u.z); v[j][3] = bf2f(u.w);
    } else {
      v[j][0] = 0.f; v[j][1] = 0.f; v[j][2] = 0.f; v[j][3] = 0.f;
    }
  }
  ushort4 gb = *reinterpret_cast<const ushort4*>(GV + (size_t)n * (2 * D_MODEL) + d0);
  float gf[4] = { bf2f(gb.x), bf2f(gb.y), bf2f(gb.z), bf2f(gb.w) };
  const float sc0 = SCL[n * 3 + 0], sc1 = SCL[n * 3 + 1], sc2 = SCL[n * 3 + 2];
  ushort4 out;
  unsigned short o[4];
  #pragma unroll
  for (int i = 0; i < 4; ++i) {
    const int d = d0 + i;
    float c3 = W3[d*3+0]*v[4][i] + W3[d*3+1]*v[5][i] + W3[d*3+2]*v[6][i];
    float c5 = W5[d*5+0]*v[2][i] + W5[d*5+1]*v[3][i] + W5[d*5+2]*v[4][i]
             + W5[d*5+3]*v[5][i] + W5[d*5+4]*v[6][i];
    float c7 = 0.f;
    #pragma unroll
    for (int j = 0; j < 7; ++j) c7 += W7[d*7+j] * v[j][i];
    const float g = fast_sigmoid(gf[i]);
    o[i] = f2bf((sc0 * c3 + sc1 * c5 + sc2 * c7) * g);
  }
  out.x = o[0]; out.y = o[1]; out.z = o[2]; out.w = o[3];
  reinterpret_cast<ushort4*>(Y + (size_t)n * D_MODEL)[t] = out;
}

// ---------------- 256x256 BT GEMM, 2-phase/tile: C = A * B^T ----------------
// r11 = r10 minus XCD swizzle (it de-synchronized A-streaming across XCDs:
// FETCH 200->540 MB; default dispatch runs one N-panel-wave at a time so A
// stays L3-hot), plus STAGE issued before the ds_read bursts (earlier HBM
// issue). Schedule identical to r10:
//   P0(slot s): stage A(t+1,*); issue B0(4),AQ0(8),B1(4);
//     lgkm(4)->MMAQ(0,0) [B1 drains under it]; lgkm(0)->MMAQ(0,1); barrier.
//   P1(slot s): stage B(t+2,*); issue AQ1a(4),AQ1b(4);
//     lgkm(4)->rows f0,1 of (1,1)+(1,0); lgkm(0)->rows f2,3; vmcnt(4); barrier.
// Correctness: a wave passes a phase-end barrier only after its lgkm(0), so
// the single end-barrier guarantees all waves' reads of a region complete
// before any wave's next-phase restage. vmcnt(4) at P1/P3-end forces the
// next slot's full tile resident (queue = [B(t+1)4][A(t+1)4][B(t+2)4]).
// Prologue: tile0 + B(1), vmcnt(4) = steady-state entry. Final iter peeled
// with vmcnt(0) at P1-end. LDS: slot s (s<<16) | A wm-half h (h<<14) | B at
// 32768+(h<<14); row r: r*128B; 16B chunk c holds global chunk c^(r&7)
// (pre-swizzled source, XOR on read).

#define EPI_BF16      0
#define EPI_RES       1
#define EPI_SWIGLU_IL 2

#define STAGE_A(tt, h) do { \
    char* d_ = dstBase + (((tt)&1) << 16) + ((h) << 14); \
    const unsigned short* s_ = aSrc + (size_t)((h)*128) * K + (tt)*64; \
    gload16(s_, d_); gload16(s_ + (size_t)64 * K, d_ + 8192); } while(0)

#define STAGE_B(tt, h) do { \
    char* d_ = dstBase + (((tt)&1) << 16) + 32768 + ((h) << 14); \
    const unsigned short* s_ = bSrc + (size_t)((h)*32) * K + (tt)*64; \
    gload16(s_, d_); gload16(s_ + (size_t)128 * K, d_ + 8192); } while(0)

// raw ds_read_b128: base VGPR + literal offset
#define DSR(dst, base, IMM) \
  asm volatile("ds_read_b128 %0, %1 offset:" #IMM : "=v"(dst) : "v"(base))

#define RD_B0(S) do { \
  DSR(b0[0][0], bB##S##k0, 0);    DSR(b0[0][1], bB##S##k1, 0); \
  DSR(b0[1][0], bB##S##k0, 2048); DSR(b0[1][1], bB##S##k1, 2048); } while(0)

#define RD_B1(S) do { \
  DSR(b1[0][0], bB##S##k0, 16384); DSR(b1[0][1], bB##S##k1, 16384); \
  DSR(b1[1][0], bB##S##k0, 18432); DSR(b1[1][1], bB##S##k1, 18432); } while(0)

#define RD_AQ0(S) do { \
  DSR(aq[0][0], aA##S##k0, 0);    DSR(aq[0][1], aA##S##k1, 0); \
  DSR(aq[1][0], aA##S##k0, 2048); DSR(aq[1][1], aA##S##k1, 2048); \
  DSR(aq[2][0], aA##S##k0, 4096); DSR(aq[2][1], aA##S##k1, 4096); \
  DSR(aq[3][0], aA##S##k0, 6144); DSR(aq[3][1], aA##S##k1, 6144); } while(0)

#define RD_AQ1A(S) do { \
  DSR(aq[0][0], aA##S##k0, 8192);  DSR(aq[0][1], aA##S##k1, 8192); \
  DSR(aq[1][0], aA##S##k0, 10240); DSR(aq[1][1], aA##S##k1, 10240); } while(0)

#define RD_AQ1B(S) do { \
  DSR(aq[2][0], aA##S##k0, 12288); DSR(aq[2][1], aA##S##k1, 12288); \
  DSR(aq[3][0], aA##S##k0, 14336); DSR(aq[3][1], aA##S##k1, 14336); } while(0)

#define MMAQ(BR, MQ, NQ) do { \
  _Pragma("unroll") for (int f_ = 0; f_ < 4; ++f_) \
  _Pragma("unroll") for (int e_ = 0; e_ < 2; ++e_) { \
    acc[(MQ)*4+f_][(NQ)*2+e_] = __builtin_amdgcn_mfma_f32_16x16x32_bf16( \
        aq[f_][0], BR[e_][0], acc[(MQ)*4+f_][(NQ)*2+e_], 0, 0, 0); \
    acc[(MQ)*4+f_][(NQ)*2+e_] = __builtin_amdgcn_mfma_f32_16x16x32_bf16( \
        aq[f_][1], BR[e_][1], acc[(MQ)*4+f_][(NQ)*2+e_], 0, 0, 0); \
  } } while(0)

#define MMAQH(BR, MQ, NQ, F0) do { \
  _Pragma("unroll") for (int f_ = (F0); f_ < (F0) + 2; ++f_) \
  _Pragma("unroll") for (int e_ = 0; e_ < 2; ++e_) { \
    acc[(MQ)*4+f_][(NQ)*2+e_] = __builtin_amdgcn_mfma_f32_16x16x32_bf16( \
        aq[f_][0], BR[e_][0], acc[(MQ)*4+f_][(NQ)*2+e_], 0, 0, 0); \
    acc[(MQ)*4+f_][(NQ)*2+e_] = __builtin_amdgcn_mfma_f32_16x16x32_bf16( \
        aq[f_][1], BR[e_][1], acc[(MQ)*4+f_][(NQ)*2+e_], 0, 0, 0); \
  } } while(0)

#define GATE4 do { asm volatile("s_waitcnt lgkmcnt(4)" ::: "memory"); \
                   __builtin_amdgcn_sched_barrier(0); } while(0)
#define GATE0 do { asm volatile("s_waitcnt lgkmcnt(0)" ::: "memory"); \
                   __builtin_amdgcn_sched_barrier(0); } while(0)
#define VM4   asm volatile("s_waitcnt vmcnt(4)" ::: "memory")
#define VM0   asm volatile("s_waitcnt vmcnt(0)" ::: "memory")
#define BAR   __builtin_amdgcn_s_barrier()
#define PRIO1 __builtin_amdgcn_s_setprio(1)
#define PRIO0 __builtin_amdgcn_s_setprio(0)

template<int EPI>
__global__ __launch_bounds__(512, 2) void gemm256_k(
    const unsigned short* __restrict__ A,
    const unsigned short* __restrict__ B0g,
    const float* __restrict__ RES,
    void* __restrict__ OUT,
    int M, int N, int K)
{
  __shared__ uint4 lds4[8192];   // 128 KB, LDS offset 0
  char* lbase = (char*)lds4;

  const int tid  = threadIdx.x;
  const int lane = tid & 63;
  const int wid  = tid >> 6;
  const int wm   = wid >> 2;        // 0..1
  const int wn   = wid & 3;         // 0..3
  const int l15 = lane & 15, l4 = lane >> 4, l7 = lane & 7;
  const int m0 = blockIdx.x * 256;  // direct mapping (no XCD swizzle, r11)
  const int n0 = blockIdx.y * 256;
  const int nt = K >> 6;            // even (16 or 64 here)

  // staging: thread covers local row r0=tid>>3 (+64 for 2nd load), chunk slot
  // tid&7 which must hold global chunk (tid&7)^(r0&7)  (pre-swizzled source).
  const int r0 = tid >> 3;
  const int kc = (tid & 7) ^ (r0 & 7);
  const unsigned short* aSrc = A + (size_t)(m0 + r0) * K + kc * 8;
  const unsigned short* bSrc = B0g + (size_t)(n0 + (r0 >> 5) * 64 + (r0 & 31)) * K + kc * 8;
  char* dstBase = lbase + tid * 16;

  // fragment-read base addresses (raw LDS byte offsets; object at offset 0)
  const unsigned colswz = (unsigned)((l4 ^ l7) << 4);
  const unsigned aA0k0 = (unsigned)((wm << 14) + l15 * 128) + colswz;
  const unsigned aA0k1 = aA0k0 ^ 0x40u;        // kk=1: chunk (4+l4)^l7 = (l4^l7)^4
  const unsigned aA1k0 = aA0k0 + 65536u;
  const unsigned aA1k1 = aA0k1 + 65536u;
  const unsigned bB0k0 = (unsigned)(32768 + (wn * 32 + l15) * 128) + colswz;
  const unsigned bB0k1 = bB0k0 ^ 0x40u;
  const unsigned bB1k0 = bB0k0 + 65536u;       // slot1 B base
  const unsigned bB1k1 = bB0k1 + 65536u;

  f32x4 acc[8][4];
  #pragma unroll
  for (int i = 0; i < 8; ++i)
    #pragma unroll
    for (int j = 0; j < 4; ++j)
      #pragma unroll
      for (int r = 0; r < 4; ++r) acc[i][j][r] = 0.f;

  bf16x8 aq[4][2], b0[2][2], b1[2][2];

  // prologue: tile0 (8 loads) then B(1,*) (4) -> vmcnt(4): tile0 resident,
  // B(1) may fly = steady-state entry condition.
  STAGE_A(0, 0); STAGE_A(0, 1); STAGE_B(0, 0); STAGE_B(0, 1);
  STAGE_B(1, 0); STAGE_B(1, 1);
  VM4;
  BAR;

  // -------- main loop (full prefetch depth) --------
  for (int t = 0; t + 2 < nt; t += 2) {
    // P0: slot0 row0
    STAGE_A(t + 1, 0); STAGE_A(t + 1, 1);
    RD_B0(0); RD_AQ0(0); RD_B1(0);
    GATE4; PRIO1; MMAQ(b0, 0, 0); PRIO0;
    GATE0; PRIO1; MMAQ(b1, 0, 1); PRIO0;
    BAR;
    // P1: slot0 row1
    STAGE_B(t + 2, 0); STAGE_B(t + 2, 1);
    RD_AQ1A(0); RD_AQ1B(0);
    GATE4; PRIO1; MMAQH(b1, 1, 1, 0); MMAQH(b0, 1, 0, 0); PRIO0;
    GATE0; PRIO1; MMAQH(b1, 1, 1, 2); MMAQH(b0, 1, 0, 2); PRIO0;
    VM4;
    BAR;
    // P2: slot1 row0
    STAGE_A(t + 2, 0); STAGE_A(t + 2, 1);
    RD_B0(1); RD_AQ0(1); RD_B1(1);
    GATE4; PRIO1; MMAQ(b0, 0, 0); PRIO0;
    GATE0; PRIO1; MMAQ(b1, 0, 1); PRIO0;
    BAR;
    // P3: slot1 row1
    STAGE_B(t + 3, 0); STAGE_B(t + 3, 1);
    RD_AQ1A(1); RD_AQ1B(1);
    GATE4; PRIO1; MMAQH(b1, 1, 1, 0); MMAQH(b0, 1, 0, 0); PRIO0;
    GATE0; PRIO1; MMAQH(b1, 1, 1, 2); MMAQH(b0, 1, 0, 2); PRIO0;
    VM4;
    BAR;
  }

  // -------- peeled final iteration (t = nt-2) --------
  {
    // P0: stages A(nt-1) (in range)
    STAGE_A(nt - 1, 0); STAGE_A(nt - 1, 1);
    RD_B0(0); RD_AQ0(0); RD_B1(0);
    GATE4; PRIO1; MMAQ(b0, 0, 0); PRIO0;
    GATE0; PRIO1; MMAQ(b1, 0, 1); PRIO0;
    BAR;
    // P1: no stages; queue is only 8 deep -> drain fully so slot1 resident
    RD_AQ1A(0); RD_AQ1B(0);
    GATE4; PRIO1; MMAQH(b1, 1, 1, 0); MMAQH(b0, 1, 0, 0); PRIO0;
    GATE0; PRIO1; MMAQH(b1, 1, 1, 2); MMAQH(b0, 1, 0, 2); PRIO0;
    VM0;
    BAR;
    // P2
    RD_B0(1); RD_AQ0(1); RD_B1(1);
    GATE4; PRIO1; MMAQ(b0, 0, 0); PRIO0;
    GATE0; PRIO1; MMAQ(b1, 0, 1); PRIO0;
    BAR;
    // P3
    RD_AQ1A(1); RD_AQ1B(1);
    GATE4; PRIO1; MMAQH(b1, 1, 1, 0); MMAQH(b0, 1, 0, 0); PRIO0;
    GATE0; PRIO1; MMAQH(b1, 1, 1, 2); MMAQH(b0, 1, 0, 2); PRIO0;
    BAR;
  }

  // keep LDS stores observable (never taken; M>0 always) — prevents DCE of
  // global_load_lds since no compiler-visible LDS reads remain.
  if (M < -1) ((float*)OUT)[tid] = ((float*)lds4)[tid];

  // epilogue: C/D fragment layout col=lane&15, row=(lane>>4)*4+rr
  const int cr = (lane >> 4) * 4;
  const int cc = lane & 15;
  if (EPI == EPI_SWIGLU_IL) {
    // 16-group interleave: E even holds g, E odd holds u for the SAME
    // ff = (n0+wn*64)/2 + (E>>1)*16 + cc. No shfl needed.
    const int ffbase = (n0 + wn * 64) >> 1;
    #pragma unroll
    for (int F = 0; F < 8; ++F)
      #pragma unroll
      for (int p = 0; p < 2; ++p)
        #pragma unroll
        for (int rr = 0; rr < 4; ++rr) {
          const int grow = m0 + wm * 128 + (F >> 2) * 64 + (F & 3) * 16 + cr + rr;
          const float g = acc[F][2 * p][rr];
          const float u = acc[F][2 * p + 1][rr];
          const float o = g * fast_sigmoid(g) * u;
          ((unsigned short*)OUT)[(size_t)grow * D_FF + ffbase + p * 16 + cc] = f2bf(o);
        }
  } else {
    #pragma unroll
    for (int F = 0; F < 8; ++F)
      #pragma unroll
      for (int E = 0; E < 4; ++E)
        #pragma unroll
        for (int rr = 0; rr < 4; ++rr) {
          const int grow = m0 + wm * 128 + (F >> 2) * 64 + (F & 3) * 16 + cr + rr;
          const int gcol = n0 + wn * 64 + (E >> 1) * 32 + (E & 1) * 16 + cc;
          const float v = acc[F][E][rr];
          if (EPI == EPI_BF16) {
            ((unsigned short*)OUT)[(size_t)grow * N + gcol] = f2bf(v);
          } else {  // EPI_RES
            const size_t idx = (size_t)grow * N + gcol;
            ((float*)OUT)[idx] = RES[idx] + v;
          }
        }
  }
}

// ---------------- launch ----------------
extern "C" void kernel_launch(void* const* d_in, const int* in_sizes, int n_in,
                              void* d_out, int out_size, void* d_ws, size_t ws_size,
                              hipStream_t stream)
{
  const float* x    = (const float*)d_in[0];
  const float* ln1w = (const float*)d_in[1];
  const float* ln2w = (const float*)d_in[2];
  const float* wf   = (const float*)d_in[3];
  const float* wm   = (const float*)d_in[4];
  const float* wco  = (const float*)d_in[5];
  const float* sgw  = (const float*)d_in[6];
  const float* upw  = (const float*)d_in[7];   // [2048,1024]
  const float* dnw  = (const float*)d_in[8];   // [1024,1024]
  const float* wg   = (const float*)d_in[9];   // [4096,1024]
  const float* wu   = (const float*)d_in[10];  // [4096,1024]
  const float* wo   = (const float*)d_in[11];  // [1024,4096]

  char* ws = (char*)d_ws;
  size_t off = 0;
  auto alloc = [&](size_t bytes) -> void* {
    void* p = ws + off;
    off += (bytes + 255) & ~(size_t)255;
    return p;
  };
  unsigned short* wb_up = (unsigned short*)alloc((size_t)2048 * 1024 * 2);
  unsigned short* wb_dn = (unsigned short*)alloc((size_t)1024 * 1024 * 2);
  unsigned short* wb_il = (unsigned short*)alloc((size_t)8192 * 1024 * 2);  // interleaved wg/wu
  unsigned short* wb_wo = (unsigned short*)alloc((size_t)1024 * 4096 * 2);
  float*          scl   = (float*)alloc((size_t)NTOK * 3 * 4);
  unsigned short* h2b   = (unsigned short*)alloc((size_t)NTOK * D_MODEL * 2);
  // 128MB region: h | gv | y live before the SwiGLU GEMM; gu aliases all three afterwards
  char* big = (char*)alloc((size_t)NTOK * 4096 * 2);
  unsigned short* hb  = (unsigned short*)big;                                  // [NTOK,1024]
  unsigned short* gvb = (unsigned short*)(big + (size_t)NTOK * 1024 * 2);      // [NTOK,2048]
  unsigned short* yb  = (unsigned short*)(big + (size_t)NTOK * 3072 * 2);      // [NTOK,1024]
  unsigned short* gub = (unsigned short*)big;                                  // [NTOK,4096]
  float* x1 = (float*)d_out;  // x after first residual lives in d_out

  // all weights -> bf16 in one launch (up | dn | wo | interleaved wg/wu)
  cvt_all_k<<<15360, 256, 0, stream>>>(upw, dnw, wo, wg, wu,
                                       wb_up, wb_dn, wb_wo, wb_il);

  // 1) h = rmsnorm(x, ln1); scale_w = softmax(h @ sg_w^T)
  rmsnorm_k<true><<<NTOK, 256, 0, stream>>>(x, ln1w, sgw, hb, scl);
  // 2) gv = h @ up_w^T  [NTOK, 2048] bf16
  gemm256_k<EPI_BF16><<<dim3(64, 8), 512, 0, stream>>>(hb, wb_up, nullptr, gvb, NTOK, 2048, 1024);
  // 3) y = (sum_k scale_k * conv_k(val)) * sigmoid(gate)
  conv_k<<<NTOK, 256, 0, stream>>>(gvb, scl, wf, wm, wco, yb);
  // 4) x1 = x + y @ down_w^T
  gemm256_k<EPI_RES><<<dim3(64, 4), 512, 0, stream>>>(yb, wb_dn, x, x1, NTOK, 1024, 1024);
  // 5) h2 = rmsnorm(x1, ln2)
  rmsnorm_k<false><<<NTOK, 256, 0, stream>>>(x1, ln2w, nullptr, h2b, nullptr);
  // 6) gu = silu(h2 @ wg^T) * (h2 @ wu^T) via 16-group interleaved GEMM [NTOK, 4096] bf16
  gemm256_k<EPI_SWIGLU_IL><<<dim3(64, 32), 512, 0, stream>>>(h2b, wb_il, nullptr, gub, NTOK, 8192, 1024);
  // 7) out = x1 + gu @ wo^T
  gemm256_k<EPI_RES><<<dim3(64, 4), 512, 0, stream>>>(gub, wb_wo, x1, (float*)d_out, NTOK, 1024, 4096);
}